// Round 3
// baseline (2582.342 us; speedup 1.0000x reference)
//
#include <hip/hip_runtime.h>

#define H 2048
#define TT 4096
#define BB 4
#define NROWS (BB * TT)               // 16384
#define NTH ((size_t)NROWS * H)       // 33,554,432
#define KCAT (H + 32)                 // 2080

typedef __attribute__((ext_vector_type(8))) short bh8;
typedef __attribute__((ext_vector_type(4))) float f32x4;

__device__ inline unsigned short f2bf(float f) {
    union { float f; unsigned u; } v; v.f = f;
    unsigned r = v.u + 0x7fff + ((v.u >> 16) & 1);   // RNE
    return (unsigned short)(r >> 16);
}

// ---------------- prep: shifted & xin (bf16), vectorized ----------------
__global__ __launch_bounds__(256) void prep_kernel(
    const float* __restrict__ hidden, const float* __restrict__ attn_x,
    const float* __restrict__ tmx,
    unsigned short* __restrict__ shifted, unsigned short* __restrict__ xin) {
    size_t i = ((size_t)blockIdx.x * 256 + threadIdx.x) * 4;
    int n = (int)(i >> 11);
    int h = (int)(i & 2047);
    int t = n & (TT - 1);
    float4 x = *(const float4*)(hidden + i);
    float4 s;
    if (t == 0) {
        int b = n >> 12;
        s = *(const float4*)(attn_x + ((size_t)b << 11) + h);
    } else {
        s = *(const float4*)(hidden + (i - H));
    }
    float4 m = *(const float4*)(tmx + h);
    ushort4 sh, xi;
    sh.x = f2bf(s.x); sh.y = f2bf(s.y); sh.z = f2bf(s.z); sh.w = f2bf(s.w);
    xi.x = f2bf(x.x + (s.x - x.x) * m.x);
    xi.y = f2bf(x.y + (s.y - x.y) * m.y);
    xi.z = f2bf(x.z + (s.z - x.z) * m.z);
    xi.w = f2bf(x.w + (s.w - x.w) * m.w);
    *(ushort4*)(shifted + i) = sh;
    *(ushort4*)(xin + i) = xi;
}

// ---------------- transpose fp32 (R x C) -> bf16 (C x R), out ld = ldo ----
__global__ __launch_bounds__(256) void transpose_kernel(
    const float* __restrict__ in, unsigned short* __restrict__ outp,
    int R, int C, int ldo) {
    __shared__ float tile[32][33];
    int tx = threadIdx.x & 31, ty = threadIdx.x >> 5;
    int r0 = blockIdx.y * 32, c0 = blockIdx.x * 32;
    for (int i = ty; i < 32; i += 8) {
        int r = r0 + i, c = c0 + tx;
        tile[i][tx] = (r < R && c < C) ? in[(size_t)r * C + c] : 0.f;
    }
    __syncthreads();
    for (int i = ty; i < 32; i += 8) {
        int c = c0 + i, r = r0 + tx;
        if (c < C && r < R) outp[(size_t)c * ldo + r] = f2bf(tile[tx][i]);
    }
}

// ------------- W2W: (32 x H fp32) @ (H x D fp32) -> bf16 into Bt cols [H..H+32) -
__global__ __launch_bounds__(256) void w2w_kernel(
    const float* __restrict__ W2f, const float* __restrict__ W, int D,
    unsigned short* __restrict__ dst, int ldb) {
    __shared__ float lds[8 * H];
    const int tid = threadIdx.x;
    const int rg = blockIdx.y;             // group of 8 r's
    for (int i = tid; i < 8 * H; i += 256) lds[i] = W2f[(size_t)rg * 8 * H + i];
    __syncthreads();
    int d = blockIdx.x * 256 + tid;
    if (d >= D) return;
    float a[8] = {0, 0, 0, 0, 0, 0, 0, 0};
    for (int hh = 0; hh < H; ++hh) {
        float w = W[(size_t)hh * D + d];
#pragma unroll
        for (int r = 0; r < 8; ++r) a[r] += lds[r * H + hh] * w;
    }
#pragma unroll
    for (int r = 0; r < 8; ++r)
        dst[(size_t)d * ldb + H + rg * 8 + r] = f2bf(a[r]);
}

// ------------- bias_f[d] = sum_h maa[h] * W[h,d]  (fp32) -----------------
__global__ __launch_bounds__(256) void bias_kernel(
    const float* __restrict__ maa, const float* __restrict__ W, int D,
    float* __restrict__ outb) {
    int d = blockIdx.x * 256 + threadIdx.x;
    if (d >= D) return;
    float a = 0.f;
    for (int hh = 0; hh < H; ++hh) a += maa[hh] * W[(size_t)hh * D + d];
    outb[d] = a;
}

// ---------------- MFMA GEMM: C = [A | A2] @ Bt^T (+bias)(+act) ------------
// A (M x KS, lda), A2 (M x (K-KS), lda2), Bt row-major (N x K, ldb).
// ACT: 0 none, 1 silu, 2 tanh. OF32: 1 -> fp32 output, 0 -> bf16 output.
template <int WM, int WN, int FM, int FN, int HAS_BIAS, int ACT, int OF32>
__global__ __launch_bounds__(256) void gemm_kernel(
    const unsigned short* __restrict__ A, int lda,
    const unsigned short* __restrict__ A2, int lda2, int KS,
    const unsigned short* __restrict__ Bt, int ldb, int K,
    void* __restrict__ outp, int ldo, int NT,
    const float* __restrict__ bias) {
    static_assert(WM * WN == 4, "4 waves");
    constexpr int BM = WM * FM * 16;
    constexpr int BN = WN * FN * 16;
    __shared__ alignas(16) unsigned short As[BM * 32];
    __shared__ alignas(16) unsigned short Bs[BN * 32];

    const int nb = gridDim.x;
    const int bid = blockIdx.x;
    const int swz = (bid & 7) * (nb >> 3) + (bid >> 3);   // XCD swizzle (nb % 8 == 0)
    const int mt = swz / NT, nt = swz % NT;
    const int m0 = mt * BM, n0 = nt * BN;

    const int tid = threadIdx.x;
    const int wave = tid >> 6, lane = tid & 63;
    const int l16 = lane & 15, kh = lane >> 4;
    const int wr = wave / WN, wc = wave % WN;

    f32x4 acc[FM][FN] = {};

    constexpr int ACH = BM * 4;   // 16B chunks in A tile
    constexpr int BCH = BN * 4;
    constexpr int AIT = (ACH + 255) / 256;
    constexpr int BIT = (BCH + 255) / 256;

    for (int k0 = 0; k0 < K; k0 += 32) {
        bh8 ra[AIT], rb[BIT];
#pragma unroll
        for (int i = 0; i < AIT; ++i) {
            int c = i * 256 + tid;
            if (ACH % 256 == 0 || c < ACH) {
                int row = c >> 2, ck = c & 3;
                int kk = k0 + ck * 8;
                const unsigned short* gp = (kk < KS)
                    ? A  + (size_t)(m0 + row) * lda  + kk
                    : A2 + (size_t)(m0 + row) * lda2 + (kk - KS);
                ra[i] = *(const bh8*)gp;
            }
        }
#pragma unroll
        for (int i = 0; i < BIT; ++i) {
            int c = i * 256 + tid;
            if (BCH % 256 == 0 || c < BCH) {
                int row = c >> 2, ck = c & 3;
                rb[i] = *(const bh8*)(Bt + (size_t)(n0 + row) * ldb + k0 + ck * 8);
            }
        }
#pragma unroll
        for (int i = 0; i < AIT; ++i) {
            int c = i * 256 + tid;
            if (ACH % 256 == 0 || c < ACH) *(bh8*)(As + (size_t)c * 8) = ra[i];
        }
#pragma unroll
        for (int i = 0; i < BIT; ++i) {
            int c = i * 256 + tid;
            if (BCH % 256 == 0 || c < BCH) *(bh8*)(Bs + (size_t)c * 8) = rb[i];
        }
        __syncthreads();
        bh8 av[FM], bv[FN];
#pragma unroll
        for (int mi = 0; mi < FM; ++mi)
            av[mi] = *(const bh8*)((const char*)As + (((wr * FM + mi) * 16 + l16) * 64 + kh * 16));
#pragma unroll
        for (int ni = 0; ni < FN; ++ni)
            bv[ni] = *(const bh8*)((const char*)Bs + (((wc * FN + ni) * 16 + l16) * 64 + kh * 16));
#pragma unroll
        for (int mi = 0; mi < FM; ++mi)
#pragma unroll
            for (int ni = 0; ni < FN; ++ni)
                acc[mi][ni] = __builtin_amdgcn_mfma_f32_16x16x32_bf16(
                    av[mi], bv[ni], acc[mi][ni], 0, 0, 0);
        __syncthreads();
    }

#pragma unroll
    for (int mi = 0; mi < FM; ++mi) {
#pragma unroll
        for (int ni = 0; ni < FN; ++ni) {
            int col = n0 + (wc * FN + ni) * 16 + l16;
            float bcol = HAS_BIAS ? bias[col] : 0.f;
#pragma unroll
            for (int j = 0; j < 4; ++j) {
                int row = m0 + (wr * FM + mi) * 16 + kh * 4 + j;
                float v = acc[mi][ni][j] + bcol;
                if (ACT == 1) v = v * (1.f / (1.f + __expf(-v)));
                else if (ACT == 2) v = tanhf(v);
                if (OF32) ((float*)outp)[(size_t)row * ldo + col] = v;
                else ((unsigned short*)outp)[(size_t)row * ldo + col] = f2bf(v);
            }
        }
    }
}

// ------- td stage 2 (fp32 VALU): out = tdecay + tdmid(N x 64) @ W2d(64 x H) ----
// grid (8, 2048): bx covers cols, by covers row-groups of 8.
__global__ __launch_bounds__(256) void td2_kernel(
    const float* __restrict__ tdmid, const float* __restrict__ W2d,
    const float* __restrict__ tdecay, float* __restrict__ outp) {
    int col = blockIdx.x * 256 + threadIdx.x;
    int row0 = blockIdx.y * 8;
    float a[8] = {0, 0, 0, 0, 0, 0, 0, 0};
    for (int r = 0; r < 64; ++r) {
        float w = W2d[(size_t)r * H + col];
#pragma unroll
        for (int j = 0; j < 8; ++j)
            a[j] += tdmid[(size_t)(row0 + j) * 64 + r] * w;
    }
    float b = tdecay[col];
#pragma unroll
    for (int j = 0; j < 8; ++j)
        outp[(size_t)(row0 + j) * H + col] = a[j] + b;
}

// ---------------- attn_x_new = hidden[:, -1]  (fp32, exact) ---------------
__global__ __launch_bounds__(256) void axnew_kernel(
    const float* __restrict__ hidden, float* __restrict__ outp) {
    int i = blockIdx.x * 256 + threadIdx.x;       // 0..8191
    int b = i >> 11, h = i & 2047;
    outp[i] = hidden[((size_t)(b * TT + (TT - 1)) << 11) + h];
}

extern "C" void kernel_launch(void* const* d_in, const int* in_sizes, int n_in,
                              void* d_out, int out_size, void* d_ws, size_t ws_size,
                              hipStream_t stream) {
    const float* hidden = (const float*)d_in[0];
    const float* attn_x = (const float*)d_in[1];
    const float* tmx    = (const float*)d_in[4];
    const float* tmaa_w = (const float*)d_in[5];
    const float* tmaa_k = (const float*)d_in[6];
    const float* tmaa_v = (const float*)d_in[7];
    const float* tmaa_r = (const float*)d_in[8];
    const float* tmaa_g = (const float*)d_in[9];
    const float* W1     = (const float*)d_in[10];   // (H,160)
    const float* W2     = (const float*)d_in[11];   // (5,32,H)
    const float* tdecay = (const float*)d_in[12];   // (1,1,H)
    const float* W1d    = (const float*)d_in[13];   // (H,64)
    const float* W2d    = (const float*)d_in[14];   // (64,H)
    const float* Wr     = (const float*)d_in[16];
    const float* Wk     = (const float*)d_in[17];
    const float* Wv     = (const float*)d_in[18];
    const float* Wg     = (const float*)d_in[19];

    float* out = (float*)d_out;     // reference outputs are float32

    char* ws = (char*)d_ws;
    size_t off = 0;
    auto alloc = [&](size_t bytes) {
        char* p = ws + off;
        off = (off + bytes + 255) & ~(size_t)255;
        return p;
    };
    unsigned short* shifted = (unsigned short*)alloc(NTH * 2);
    unsigned short* xin     = (unsigned short*)alloc(NTH * 2);
    unsigned short* zbuf    = (unsigned short*)alloc((size_t)NROWS * 160 * 2);
    unsigned short* W1t     = (unsigned short*)alloc((size_t)160 * H * 2);
    unsigned short* BcatR   = (unsigned short*)alloc((size_t)H * KCAT * 2);
    unsigned short* BcatK   = (unsigned short*)alloc((size_t)H * KCAT * 2);
    unsigned short* BcatV   = (unsigned short*)alloc((size_t)H * KCAT * 2);
    unsigned short* BcatG   = (unsigned short*)alloc((size_t)H * KCAT * 2);
    unsigned short* Bcat1   = (unsigned short*)alloc((size_t)64 * KCAT * 2);
    float* tdmid            = (float*)alloc((size_t)NROWS * 64 * 4);
    float* bias4            = (float*)alloc(4 * H * 4);
    float* bias0            = (float*)alloc(64 * 4);

    // 1. shifted / xin
    prep_kernel<<<(unsigned)(NTH / (4 * 256)), 256, 0, stream>>>(hidden, attn_x, tmx, shifted, xin);

    // 2. fused weights per branch: order R(f=3), K(f=1), V(f=2), G(f=4)
    unsigned short* Bcat[4] = {BcatR, BcatK, BcatV, BcatG};
    const float* Wb[4]      = {Wr, Wk, Wv, Wg};
    const int fidx[4]       = {3, 1, 2, 4};
    const float* maab[4]    = {tmaa_r, tmaa_k, tmaa_v, tmaa_g};
    for (int i = 0; i < 4; ++i) {
        transpose_kernel<<<dim3(64, 64), 256, 0, stream>>>(Wb[i], Bcat[i], H, H, KCAT);
        w2w_kernel<<<dim3(8, 4), 256, 0, stream>>>(W2 + (size_t)fidx[i] * 32 * H, Wb[i], H, Bcat[i], KCAT);
        bias_kernel<<<8, 256, 0, stream>>>(maab[i], Wb[i], H, bias4 + i * H);
    }
    transpose_kernel<<<dim3(5, 64), 256, 0, stream>>>(W1, W1t, H, 160, H);
    transpose_kernel<<<dim3(2, 64), 256, 0, stream>>>(W1d, Bcat1, H, 64, KCAT);
    w2w_kernel<<<dim3(1, 4), 256, 0, stream>>>(W2, W1d, 64, Bcat1, KCAT);
    bias_kernel<<<1, 256, 0, stream>>>(tmaa_w, W1d, 64, bias0);

    // 3. z = tanh(xin @ W1)  (16384 x 160, bf16)
    gemm_kernel<4, 1, 2, 2, 0, 2, 0><<<640, 256, 0, stream>>>(
        xin, H, xin, H, H, W1t, H, H, zbuf, 160, 5, nullptr);

    // 4. big projections: out_f = [shifted | z_f] @ Bcat_f^T + bias_f (gate: silu)
    gemm_kernel<2, 2, 4, 4, 1, 0, 1><<<2048, 256, 0, stream>>>(
        shifted, H, zbuf + fidx[0] * 32, 160, H, BcatR, KCAT, KCAT,
        out + 0 * NTH, H, 16, bias4 + 0 * H);
    gemm_kernel<2, 2, 4, 4, 1, 0, 1><<<2048, 256, 0, stream>>>(
        shifted, H, zbuf + fidx[1] * 32, 160, H, BcatK, KCAT, KCAT,
        out + 1 * NTH, H, 16, bias4 + 1 * H);
    gemm_kernel<2, 2, 4, 4, 1, 0, 1><<<2048, 256, 0, stream>>>(
        shifted, H, zbuf + fidx[2] * 32, 160, H, BcatV, KCAT, KCAT,
        out + 2 * NTH, H, 16, bias4 + 2 * H);
    gemm_kernel<2, 2, 4, 4, 1, 1, 1><<<2048, 256, 0, stream>>>(
        shifted, H, zbuf + fidx[3] * 32, 160, H, BcatG, KCAT, KCAT,
        out + 3 * NTH, H, 16, bias4 + 3 * H);

    // 5. decay: tdmid = tanh([shifted | z_0] @ Bcat1^T + bias0)   (fp32 out)
    gemm_kernel<4, 1, 1, 4, 1, 2, 1><<<256, 256, 0, stream>>>(
        shifted, H, zbuf + 0, 160, H, Bcat1, KCAT, KCAT,
        tdmid, 64, 1, bias0);
    //    td = time_decay + tdmid @ W2d   (fp32 VALU, register-blocked)
    td2_kernel<<<dim3(8, NROWS / 8), 256, 0, stream>>>(
        tdmid, W2d, tdecay, out + 4 * NTH);

    // 6. attn_x_new (exact fp32 copy)
    axnew_kernel<<<32, 256, 0, stream>>>(hidden, out + 5 * NTH);
}

// Round 4
// 1997.054 us; speedup vs baseline: 1.2931x; 1.2931x over previous
//
#include <hip/hip_runtime.h>

#define H 2048
#define TT 4096
#define BB 4
#define NROWS (BB * TT)               // 16384
#define NTH ((size_t)NROWS * H)       // 33,554,432
#define KCAT (H + 32)                 // 2080

typedef __attribute__((ext_vector_type(8))) short bh8;
typedef __attribute__((ext_vector_type(4))) float f32x4;

__device__ inline unsigned short f2bf(float f) {
    union { float f; unsigned u; } v; v.f = f;
    unsigned r = v.u + 0x7fff + ((v.u >> 16) & 1);   // RNE
    return (unsigned short)(r >> 16);
}
__device__ inline float bf2f(unsigned short u) {
    union { unsigned u; float f; } v; v.u = ((unsigned)u) << 16; return v.f;
}
__device__ inline void gload_lds16(const void* g, void* l) {
    __builtin_amdgcn_global_load_lds(
        (const __attribute__((address_space(1))) void*)g,
        (__attribute__((address_space(3))) void*)l, 16, 0, 0);
}

// ---------------- prep: shifted & xin (bf16), vectorized ----------------
__global__ __launch_bounds__(256) void prep_kernel(
    const float* __restrict__ hidden, const float* __restrict__ attn_x,
    const float* __restrict__ tmx,
    unsigned short* __restrict__ shifted, unsigned short* __restrict__ xin) {
    size_t i = ((size_t)blockIdx.x * 256 + threadIdx.x) * 4;
    int n = (int)(i >> 11);
    int h = (int)(i & 2047);
    int t = n & (TT - 1);
    float4 x = *(const float4*)(hidden + i);
    float4 s;
    if (t == 0) {
        int b = n >> 12;
        s = *(const float4*)(attn_x + ((size_t)b << 11) + h);
    } else {
        s = *(const float4*)(hidden + (i - H));
    }
    float4 m = *(const float4*)(tmx + h);
    ushort4 sh, xi;
    sh.x = f2bf(s.x); sh.y = f2bf(s.y); sh.z = f2bf(s.z); sh.w = f2bf(s.w);
    xi.x = f2bf(x.x + (s.x - x.x) * m.x);
    xi.y = f2bf(x.y + (s.y - x.y) * m.y);
    xi.z = f2bf(x.z + (s.z - x.z) * m.z);
    xi.w = f2bf(x.w + (s.w - x.w) * m.w);
    *(ushort4*)(shifted + i) = sh;
    *(ushort4*)(xin + i) = xi;
}

// ---------------- transpose fp32 (R x C) -> bf16 (C x R), out ld = ldo ----
__global__ __launch_bounds__(256) void transpose_kernel(
    const float* __restrict__ in, unsigned short* __restrict__ outp,
    int R, int C, int ldo) {
    __shared__ float tile[32][33];
    int tx = threadIdx.x & 31, ty = threadIdx.x >> 5;
    int r0 = blockIdx.y * 32, c0 = blockIdx.x * 32;
    for (int i = ty; i < 32; i += 8) {
        int r = r0 + i, c = c0 + tx;
        tile[i][tx] = (r < R && c < C) ? in[(size_t)r * C + c] : 0.f;
    }
    __syncthreads();
    for (int i = ty; i < 32; i += 8) {
        int c = c0 + i, r = r0 + tx;
        if (c < C && r < R) outp[(size_t)c * ldo + r] = f2bf(tile[tx][i]);
    }
}

// ------------- W2W: (32 x H fp32) @ (H x D fp32) -> bf16 into Bt cols [H..H+32) -
__global__ __launch_bounds__(256) void w2w_kernel(
    const float* __restrict__ W2f, const float* __restrict__ W, int D,
    unsigned short* __restrict__ dst, int ldb) {
    __shared__ float lds[8 * H];
    const int tid = threadIdx.x;
    const int rg = blockIdx.y;             // group of 8 r's
    for (int i = tid; i < 8 * H; i += 256) lds[i] = W2f[(size_t)rg * 8 * H + i];
    __syncthreads();
    int d = blockIdx.x * 256 + tid;
    if (d >= D) return;
    float a[8] = {0, 0, 0, 0, 0, 0, 0, 0};
    for (int hh = 0; hh < H; ++hh) {
        float w = W[(size_t)hh * D + d];
#pragma unroll
        for (int r = 0; r < 8; ++r) a[r] += lds[r * H + hh] * w;
    }
#pragma unroll
    for (int r = 0; r < 8; ++r)
        dst[(size_t)d * ldb + H + rg * 8 + r] = f2bf(a[r]);
}

// -------- bias (merged): wave per row; bias[d] = dot(maa, W[:,d]) via Bcat rows --
__global__ __launch_bounds__(256) void bias_all_kernel(
    const unsigned short* __restrict__ bR, const unsigned short* __restrict__ bK,
    const unsigned short* __restrict__ bV, const unsigned short* __restrict__ bG,
    const unsigned short* __restrict__ b1,
    const float* __restrict__ mR, const float* __restrict__ mK,
    const float* __restrict__ mV, const float* __restrict__ mG,
    const float* __restrict__ mW,
    float* __restrict__ bias4, float* __restrict__ bias0) {
    int wave = threadIdx.x >> 6, lane = threadIdx.x & 63;
    int p = blockIdx.x * 4 + wave;          // 0..8255
    const unsigned short* src; const float* maa; float* dst;
    if (p < 8192) {
        int br = p >> 11, row = p & 2047;
        src = (br == 0 ? bR : br == 1 ? bK : br == 2 ? bV : bG) + (size_t)row * KCAT;
        maa = (br == 0 ? mR : br == 1 ? mK : br == 2 ? mV : mG);
        dst = bias4 + br * H + row;
    } else {
        int q = p - 8192;
        if (q >= 64) return;
        src = b1 + (size_t)q * KCAT; maa = mW; dst = bias0 + q;
    }
    float a = 0.f;
#pragma unroll 4
    for (int i = 0; i < 32; ++i) { int h = i * 64 + lane; a += bf2f(src[h]) * maa[h]; }
    for (int s = 32; s; s >>= 1) a += __shfl_xor(a, s);
    if (lane == 0) *dst = a;
}

// ---------------- shared MFMA GEMM core (global_load_lds staging) ---------
// C-tile accum for [A | A2] @ Bt^T ; A (M x KS, lda), A2 (ld lda2), Bt (N x K, ldb).
template <int WM, int WN, int FM, int FN>
__device__ __forceinline__ void gemm_core(
    const unsigned short* __restrict__ A, int lda,
    const unsigned short* __restrict__ A2, int lda2, int KS,
    const unsigned short* __restrict__ Bt, int ldb, int K,
    int m0, int n0, f32x4 (&acc)[FM][FN],
    unsigned short* As, unsigned short* Bs) {
    constexpr int BM = WM * FM * 16;
    constexpr int BN = WN * FN * 16;
    const int tid = threadIdx.x;
    const int wave = tid >> 6, lane = tid & 63;
    const int l16 = lane & 15, kh = lane >> 4;
    const int wr = wave / WN, wc = wave % WN;
    constexpr int ACH = BM * 4;   // 16B chunks in A tile
    constexpr int BCH = BN * 4;

    for (int k0 = 0; k0 < K; k0 += 32) {
#pragma unroll
        for (int i = 0; i < (ACH + 255) / 256; ++i) {
            int c = i * 256 + tid;
            if (ACH % 256 == 0 || c < ACH) {
                int row = c >> 2, ck = c & 3;
                int kk = k0 + ck * 8;
                const unsigned short* gp = (kk < KS)
                    ? A  + (size_t)(m0 + row) * lda  + kk
                    : A2 + (size_t)(m0 + row) * lda2 + (kk - KS);
                gload_lds16(gp, As + (size_t)(i * 256 + wave * 64) * 8);
            }
        }
#pragma unroll
        for (int i = 0; i < (BCH + 255) / 256; ++i) {
            int c = i * 256 + tid;
            if (BCH % 256 == 0 || c < BCH) {
                int row = c >> 2, ck = c & 3;
                gload_lds16(Bt + (size_t)(n0 + row) * ldb + k0 + ck * 8,
                            Bs + (size_t)(i * 256 + wave * 64) * 8);
            }
        }
        __syncthreads();
        bh8 av[FM], bv[FN];
#pragma unroll
        for (int mi = 0; mi < FM; ++mi)
            av[mi] = *(const bh8*)((const char*)As + (((wr * FM + mi) * 16 + l16) * 64 + kh * 16));
#pragma unroll
        for (int ni = 0; ni < FN; ++ni)
            bv[ni] = *(const bh8*)((const char*)Bs + (((wc * FN + ni) * 16 + l16) * 64 + kh * 16));
#pragma unroll
        for (int mi = 0; mi < FM; ++mi)
#pragma unroll
            for (int ni = 0; ni < FN; ++ni)
                acc[mi][ni] = __builtin_amdgcn_mfma_f32_16x16x32_bf16(
                    av[mi], bv[ni], acc[mi][ni], 0, 0, 0);
        __syncthreads();
    }
}

// ---------------- generic GEMM kernel (z, tdmid) --------------------------
template <int WM, int WN, int FM, int FN, int HAS_BIAS, int ACT, int OF32>
__global__ __launch_bounds__(256) void gemm_kernel(
    const unsigned short* __restrict__ A, int lda,
    const unsigned short* __restrict__ A2, int lda2, int KS,
    const unsigned short* __restrict__ Bt, int ldb, int K,
    void* __restrict__ outp, int ldo, int NT,
    const float* __restrict__ bias) {
    static_assert(WM * WN == 4, "4 waves");
    constexpr int BM = WM * FM * 16;
    constexpr int BN = WN * FN * 16;
    __shared__ unsigned short As[BM * 32];
    __shared__ unsigned short Bs[BN * 32];

    const int nb = gridDim.x;
    const int bid = blockIdx.x;
    const int swz = (bid & 7) * (nb >> 3) + (bid >> 3);   // nb % 8 == 0
    const int mt = swz / NT, nt = swz % NT;
    const int m0 = mt * BM, n0 = nt * BN;

    f32x4 acc[FM][FN] = {};
    gemm_core<WM, WN, FM, FN>(A, lda, A2, lda2, KS, Bt, ldb, K, m0, n0, acc, As, Bs);

    const int tid = threadIdx.x;
    const int wave = tid >> 6, lane = tid & 63;
    const int l16 = lane & 15, kh = lane >> 4;
    const int wr = wave / WN, wc = wave % WN;
#pragma unroll
    for (int mi = 0; mi < FM; ++mi) {
#pragma unroll
        for (int ni = 0; ni < FN; ++ni) {
            int col = n0 + (wc * FN + ni) * 16 + l16;
            float bcol = HAS_BIAS ? bias[col] : 0.f;
#pragma unroll
            for (int j = 0; j < 4; ++j) {
                int row = m0 + (wr * FM + mi) * 16 + kh * 4 + j;
                float v = acc[mi][ni][j] + bcol;
                if (ACT == 1) v = v * (1.f / (1.f + __expf(-v)));
                else if (ACT == 2) v = tanhf(v);
                if (OF32) ((float*)outp)[(size_t)row * ldo + col] = v;
                else ((unsigned short*)outp)[(size_t)row * ldo + col] = f2bf(v);
            }
        }
    }
}

// ---------------- merged big projections (R,K,V,G in one launch) ----------
__global__ __launch_bounds__(256) void bigproj_kernel(
    const unsigned short* __restrict__ A,     // shifted, lda = H
    const unsigned short* __restrict__ zbuf,  // ld 160
    const unsigned short* __restrict__ bt0, const unsigned short* __restrict__ bt1,
    const unsigned short* __restrict__ bt2, const unsigned short* __restrict__ bt3,
    const float* __restrict__ bias4, float* __restrict__ out) {
    constexpr int WM = 2, WN = 2, FM = 4, FN = 4, BM = 128, BN = 128;
    __shared__ unsigned short As[BM * 32];
    __shared__ unsigned short Bs[BN * 32];

    const int bid = blockIdx.x;                      // 8192 blocks
    const int swz = (bid & 7) * 1024 + (bid >> 3);   // bijective, 8192 % 8 == 0
    const int branch = swz >> 11;                    // 0..3 = R,K,V,G
    const int tile = swz & 2047;
    const int m0 = (tile >> 4) * BM, n0 = (tile & 15) * BN;

    const unsigned short* Bt = branch == 0 ? bt0 : branch == 1 ? bt1
                             : branch == 2 ? bt2 : bt3;
    const int f = (0x4213 >> (branch * 4)) & 15;     // fidx {3,1,2,4}
    const unsigned short* A2 = zbuf + f * 32;

    f32x4 acc[FM][FN] = {};
    gemm_core<WM, WN, FM, FN>(A, H, A2, 160, H, Bt, KCAT, KCAT, m0, n0, acc, As, Bs);

    const int tid = threadIdx.x;
    const int wave = tid >> 6, lane = tid & 63;
    const int l16 = lane & 15, kh = lane >> 4;
    const int wr = wave >> 1, wc = wave & 1;
    float* outp = out + (size_t)branch * NTH;
    const float* bias = bias4 + branch * H;
#pragma unroll
    for (int mi = 0; mi < FM; ++mi) {
#pragma unroll
        for (int ni = 0; ni < FN; ++ni) {
            int col = n0 + (wc * FN + ni) * 16 + l16;
            float bcol = bias[col];
#pragma unroll
            for (int j = 0; j < 4; ++j) {
                int row = m0 + (wr * FM + mi) * 16 + kh * 4 + j;
                float v = acc[mi][ni][j] + bcol;
                if (branch == 3) v = v * (1.f / (1.f + __expf(-v)));   // silu (gate)
                outp[(size_t)row * H + col] = v;
            }
        }
    }
}

// ------- td stage 2 (fp32 VALU): out = tdecay + tdmid(N x 64) @ W2d(64 x H) ----
__global__ __launch_bounds__(256) void td2_kernel(
    const float* __restrict__ tdmid, const float* __restrict__ W2d,
    const float* __restrict__ tdecay, float* __restrict__ outp) {
    int col = blockIdx.x * 256 + threadIdx.x;
    int row0 = blockIdx.y * 8;
    float a[8] = {0, 0, 0, 0, 0, 0, 0, 0};
    for (int r = 0; r < 64; ++r) {
        float w = W2d[(size_t)r * H + col];
#pragma unroll
        for (int j = 0; j < 8; ++j)
            a[j] += tdmid[(size_t)(row0 + j) * 64 + r] * w;
    }
    float b = tdecay[col];
#pragma unroll
    for (int j = 0; j < 8; ++j)
        outp[(size_t)(row0 + j) * H + col] = a[j] + b;
}

// ---------------- attn_x_new = hidden[:, -1]  (fp32, exact) ---------------
__global__ __launch_bounds__(256) void axnew_kernel(
    const float* __restrict__ hidden, float* __restrict__ outp) {
    int i = blockIdx.x * 256 + threadIdx.x;       // 0..8191
    int b = i >> 11, h = i & 2047;
    outp[i] = hidden[((size_t)(b * TT + (TT - 1)) << 11) + h];
}

extern "C" void kernel_launch(void* const* d_in, const int* in_sizes, int n_in,
                              void* d_out, int out_size, void* d_ws, size_t ws_size,
                              hipStream_t stream) {
    const float* hidden = (const float*)d_in[0];
    const float* attn_x = (const float*)d_in[1];
    const float* tmx    = (const float*)d_in[4];
    const float* tmaa_w = (const float*)d_in[5];
    const float* tmaa_k = (const float*)d_in[6];
    const float* tmaa_v = (const float*)d_in[7];
    const float* tmaa_r = (const float*)d_in[8];
    const float* tmaa_g = (const float*)d_in[9];
    const float* W1     = (const float*)d_in[10];   // (H,160)
    const float* W2     = (const float*)d_in[11];   // (5,32,H)
    const float* tdecay = (const float*)d_in[12];   // (1,1,H)
    const float* W1d    = (const float*)d_in[13];   // (H,64)
    const float* W2d    = (const float*)d_in[14];   // (64,H)
    const float* Wr     = (const float*)d_in[16];
    const float* Wk     = (const float*)d_in[17];
    const float* Wv     = (const float*)d_in[18];
    const float* Wg     = (const float*)d_in[19];

    float* out = (float*)d_out;     // reference outputs are float32

    char* ws = (char*)d_ws;
    size_t off = 0;
    auto alloc = [&](size_t bytes) {
        char* p = ws + off;
        off = (off + bytes + 255) & ~(size_t)255;
        return p;
    };
    unsigned short* shifted = (unsigned short*)alloc(NTH * 2);
    unsigned short* xin     = (unsigned short*)alloc(NTH * 2);
    unsigned short* zbuf    = (unsigned short*)alloc((size_t)NROWS * 160 * 2);
    unsigned short* W1t     = (unsigned short*)alloc((size_t)160 * H * 2);
    unsigned short* BcatR   = (unsigned short*)alloc((size_t)H * KCAT * 2);
    unsigned short* BcatK   = (unsigned short*)alloc((size_t)H * KCAT * 2);
    unsigned short* BcatV   = (unsigned short*)alloc((size_t)H * KCAT * 2);
    unsigned short* BcatG   = (unsigned short*)alloc((size_t)H * KCAT * 2);
    unsigned short* Bcat1   = (unsigned short*)alloc((size_t)64 * KCAT * 2);
    float* tdmid            = (float*)alloc((size_t)NROWS * 64 * 4);
    float* bias4            = (float*)alloc(4 * H * 4);
    float* bias0            = (float*)alloc(64 * 4);

    // 1. shifted / xin
    prep_kernel<<<(unsigned)(NTH / (4 * 256)), 256, 0, stream>>>(hidden, attn_x, tmx, shifted, xin);

    // 2. fused weights per branch: order R(f=3), K(f=1), V(f=2), G(f=4)
    unsigned short* Bcat[4] = {BcatR, BcatK, BcatV, BcatG};
    const float* Wb[4]      = {Wr, Wk, Wv, Wg};
    const int fidx[4]       = {3, 1, 2, 4};
    for (int i = 0; i < 4; ++i) {
        transpose_kernel<<<dim3(64, 64), 256, 0, stream>>>(Wb[i], Bcat[i], H, H, KCAT);
        w2w_kernel<<<dim3(8, 4), 256, 0, stream>>>(W2 + (size_t)fidx[i] * 32 * H, Wb[i], H, Bcat[i], KCAT);
    }
    transpose_kernel<<<dim3(5, 64), 256, 0, stream>>>(W1, W1t, H, 160, H);
    transpose_kernel<<<dim3(2, 64), 256, 0, stream>>>(W1d, Bcat1, H, 64, KCAT);
    w2w_kernel<<<dim3(1, 4), 256, 0, stream>>>(W2, W1d, 64, Bcat1, KCAT);

    // 2b. biases (merged, wave-per-row, reads bf16 Bcat rows)
    bias_all_kernel<<<2064, 256, 0, stream>>>(
        BcatR, BcatK, BcatV, BcatG, Bcat1,
        tmaa_r, tmaa_k, tmaa_v, tmaa_g, tmaa_w, bias4, bias0);

    // 3. z = tanh(xin @ W1)  (16384 x 160, bf16)
    gemm_kernel<4, 1, 2, 2, 0, 2, 0><<<640, 256, 0, stream>>>(
        xin, H, xin, H, H, W1t, H, H, zbuf, 160, 5, nullptr);

    // 4. big projections (merged R,K,V,G)
    bigproj_kernel<<<8192, 256, 0, stream>>>(
        shifted, zbuf, BcatR, BcatK, BcatV, BcatG, bias4, out);

    // 5. decay: tdmid = tanh([shifted | z_0] @ Bcat1^T + bias0)   (fp32 out)
    gemm_kernel<4, 1, 1, 4, 1, 2, 1><<<256, 256, 0, stream>>>(
        shifted, H, zbuf + 0, 160, H, Bcat1, KCAT, KCAT,
        tdmid, 64, 1, bias0);
    //    td = time_decay + tdmid @ W2d   (fp32 VALU, register-blocked)
    td2_kernel<<<dim3(8, NROWS / 8), 256, 0, stream>>>(
        tdmid, W2d, tdecay, out + 4 * NTH);

    // 6. attn_x_new (exact fp32 copy)
    axnew_kernel<<<32, 256, 0, stream>>>(hidden, out + 5 * NTH);
}

// Round 5
// 1303.276 us; speedup vs baseline: 1.9814x; 1.5323x over previous
//
#include <hip/hip_runtime.h>

#define H 2048
#define TT 4096
#define BB 4
#define NROWS (BB * TT)               // 16384
#define NTH ((size_t)NROWS * H)       // 33,554,432
#define KCAT (H + 32)                 // 2080 (decay path)
#define KC8  (H + 64)                 // 2112 (8-phase bigproj, zero-padded)
#define NTH64 ((size_t)NROWS * 64)

typedef __attribute__((ext_vector_type(8))) short bh8;
typedef __attribute__((ext_vector_type(4))) float f32x4;

__device__ inline unsigned short f2bf(float f) {
    union { float f; unsigned u; } v; v.f = f;
    unsigned r = v.u + 0x7fff + ((v.u >> 16) & 1);   // RNE
    return (unsigned short)(r >> 16);
}
__device__ inline float bf2f(unsigned short u) {
    union { unsigned u; float f; } v; v.u = ((unsigned)u) << 16; return v.f;
}
__device__ inline void gload_lds16(const void* g, void* l) {
    __builtin_amdgcn_global_load_lds(
        (const __attribute__((address_space(1))) void*)g,
        (__attribute__((address_space(3))) void*)l, 16, 0, 0);
}

// ---------------- prep: shifted & xin (bf16), vectorized ----------------
__global__ __launch_bounds__(256) void prep_kernel(
    const float* __restrict__ hidden, const float* __restrict__ attn_x,
    const float* __restrict__ tmx,
    unsigned short* __restrict__ shifted, unsigned short* __restrict__ xin) {
    size_t i = ((size_t)blockIdx.x * 256 + threadIdx.x) * 4;
    int n = (int)(i >> 11);
    int h = (int)(i & 2047);
    int t = n & (TT - 1);
    float4 x = *(const float4*)(hidden + i);
    float4 s;
    if (t == 0) {
        int b = n >> 12;
        s = *(const float4*)(attn_x + ((size_t)b << 11) + h);
    } else {
        s = *(const float4*)(hidden + (i - H));
    }
    float4 m = *(const float4*)(tmx + h);
    ushort4 sh, xi;
    sh.x = f2bf(s.x); sh.y = f2bf(s.y); sh.z = f2bf(s.z); sh.w = f2bf(s.w);
    xi.x = f2bf(x.x + (s.x - x.x) * m.x);
    xi.y = f2bf(x.y + (s.y - x.y) * m.y);
    xi.z = f2bf(x.z + (s.z - x.z) * m.z);
    xi.w = f2bf(x.w + (s.w - x.w) * m.w);
    *(ushort4*)(shifted + i) = sh;
    *(ushort4*)(xin + i) = xi;
}

// ---------------- transpose fp32 (R x C) -> bf16 (C x R), out ld = ldo ----
__global__ __launch_bounds__(256) void transpose_kernel(
    const float* __restrict__ in, unsigned short* __restrict__ outp,
    int R, int C, int ldo) {
    __shared__ float tile[32][33];
    int tx = threadIdx.x & 31, ty = threadIdx.x >> 5;
    int r0 = blockIdx.y * 32, c0 = blockIdx.x * 32;
    for (int i = ty; i < 32; i += 8) {
        int r = r0 + i, c = c0 + tx;
        tile[i][tx] = (r < R && c < C) ? in[(size_t)r * C + c] : 0.f;
    }
    __syncthreads();
    for (int i = ty; i < 32; i += 8) {
        int c = c0 + i, r = r0 + tx;
        if (c < C && r < R) outp[(size_t)c * ldo + r] = f2bf(tile[tx][i]);
    }
}

// ---------------- merged transpose of the 4 big weights (H x H, ldo=KC8) --
__global__ __launch_bounds__(256) void transpose4_kernel(
    const float* __restrict__ w0, const float* __restrict__ w1,
    const float* __restrict__ w2, const float* __restrict__ w3,
    unsigned short* __restrict__ d0, unsigned short* __restrict__ d1,
    unsigned short* __restrict__ d2, unsigned short* __restrict__ d3) {
    __shared__ float tile[32][33];
    int bz = blockIdx.z;
    const float* in = bz == 0 ? w0 : bz == 1 ? w1 : bz == 2 ? w2 : w3;
    unsigned short* outp = bz == 0 ? d0 : bz == 1 ? d1 : bz == 2 ? d2 : d3;
    int tx = threadIdx.x & 31, ty = threadIdx.x >> 5;
    int r0 = blockIdx.y * 32, c0 = blockIdx.x * 32;
    for (int i = ty; i < 32; i += 8)
        tile[i][tx] = in[(size_t)(r0 + i) * H + c0 + tx];
    __syncthreads();
    for (int i = ty; i < 32; i += 8)
        outp[(size_t)(c0 + i) * KC8 + r0 + tx] = f2bf(tile[tx][i]);
}

// ------ merged W2W for 4 branches: cols [H..H+32) of Bcat, zeros [H+32..H+64) -
__global__ __launch_bounds__(256) void w2w4_kernel(
    const float* __restrict__ W2,
    const float* __restrict__ w0, const float* __restrict__ w1,
    const float* __restrict__ w2, const float* __restrict__ w3,
    unsigned short* __restrict__ d0, unsigned short* __restrict__ d1,
    unsigned short* __restrict__ d2, unsigned short* __restrict__ d3) {
    __shared__ float lds[8 * H];
    int bz = blockIdx.z;
    const float* W = bz == 0 ? w0 : bz == 1 ? w1 : bz == 2 ? w2 : w3;
    unsigned short* dst = bz == 0 ? d0 : bz == 1 ? d1 : bz == 2 ? d2 : d3;
    const float* W2f = W2 + (size_t)((0x4213 >> (bz * 4)) & 15) * 32 * H;
    const int tid = threadIdx.x;
    const int rg = blockIdx.y;             // group of 8 r's
    for (int i = tid; i < 8 * H; i += 256) lds[i] = W2f[(size_t)rg * 8 * H + i];
    __syncthreads();
    int d = blockIdx.x * 256 + tid;
    float a[8] = {0, 0, 0, 0, 0, 0, 0, 0};
    for (int hh = 0; hh < H; ++hh) {
        float w = W[(size_t)hh * H + d];
#pragma unroll
        for (int r = 0; r < 8; ++r) a[r] += lds[r * H + hh] * w;
    }
#pragma unroll
    for (int r = 0; r < 8; ++r) {
        dst[(size_t)d * KC8 + H + rg * 8 + r] = f2bf(a[r]);
        dst[(size_t)d * KC8 + H + 32 + rg * 8 + r] = 0;   // zero pad
    }
}

// ------------- W2W single (decay): (32 x H) @ (H x 64) -> Bcat1 cols [H..H+32) -
__global__ __launch_bounds__(256) void w2w_kernel(
    const float* __restrict__ W2f, const float* __restrict__ W, int D,
    unsigned short* __restrict__ dst, int ldb) {
    __shared__ float lds[8 * H];
    const int tid = threadIdx.x;
    const int rg = blockIdx.y;
    for (int i = tid; i < 8 * H; i += 256) lds[i] = W2f[(size_t)rg * 8 * H + i];
    __syncthreads();
    int d = blockIdx.x * 256 + tid;
    if (d >= D) return;
    float a[8] = {0, 0, 0, 0, 0, 0, 0, 0};
    for (int hh = 0; hh < H; ++hh) {
        float w = W[(size_t)hh * D + d];
#pragma unroll
        for (int r = 0; r < 8; ++r) a[r] += lds[r * H + hh] * w;
    }
#pragma unroll
    for (int r = 0; r < 8; ++r)
        dst[(size_t)d * ldb + H + rg * 8 + r] = f2bf(a[r]);
}

// -------- bias (merged): wave per row; bias[d] = dot(maa, W[:,d]) via Bcat rows --
__global__ __launch_bounds__(256) void bias_all_kernel(
    const unsigned short* __restrict__ bR, const unsigned short* __restrict__ bK,
    const unsigned short* __restrict__ bV, const unsigned short* __restrict__ bG,
    const unsigned short* __restrict__ b1,
    const float* __restrict__ mR, const float* __restrict__ mK,
    const float* __restrict__ mV, const float* __restrict__ mG,
    const float* __restrict__ mW,
    float* __restrict__ bias4, float* __restrict__ bias0) {
    int wave = threadIdx.x >> 6, lane = threadIdx.x & 63;
    int p = blockIdx.x * 4 + wave;          // 0..8255
    const unsigned short* src; const float* maa; float* dst;
    if (p < 8192) {
        int br = p >> 11, row = p & 2047;
        src = (br == 0 ? bR : br == 1 ? bK : br == 2 ? bV : bG) + (size_t)row * KC8;
        maa = (br == 0 ? mR : br == 1 ? mK : br == 2 ? mV : mG);
        dst = bias4 + br * H + row;
    } else {
        int q = p - 8192;
        if (q >= 64) return;
        src = b1 + (size_t)q * KCAT; maa = mW; dst = bias0 + q;
    }
    float a = 0.f;
#pragma unroll 4
    for (int i = 0; i < 32; ++i) { int h = i * 64 + lane; a += bf2f(src[h]) * maa[h]; }
    for (int s = 32; s; s >>= 1) a += __shfl_xor(a, s);
    if (lane == 0) *dst = a;
}

// ---------------- old-style MFMA GEMM core (z / tdmid) --------------------
template <int WM, int WN, int FM, int FN, int HAS_BIAS, int ACT, int OF32, int ZPAD>
__global__ __launch_bounds__(256) void gemm_kernel(
    const unsigned short* __restrict__ A, int lda,
    const unsigned short* __restrict__ A2, int lda2, int KS,
    const unsigned short* __restrict__ Bt, int ldb, int K,
    void* __restrict__ outp, int ldo, int NT,
    const float* __restrict__ bias) {
    static_assert(WM * WN == 4, "4 waves");
    constexpr int BM = WM * FM * 16;
    constexpr int BN = WN * FN * 16;
    __shared__ unsigned short As[BM * 32];
    __shared__ unsigned short Bs[BN * 32];

    const int nb = gridDim.x;
    const int bid = blockIdx.x;
    const int swz = (bid & 7) * (nb >> 3) + (bid >> 3);   // nb % 8 == 0
    const int mt = swz / NT, nt = swz % NT;
    const int m0 = mt * BM, n0 = nt * BN;

    const int tid = threadIdx.x;
    const int wave = tid >> 6, lane = tid & 63;
    const int l16 = lane & 15, kh = lane >> 4;
    const int wr = wave / WN, wc = wave % WN;

    f32x4 acc[FM][FN] = {};

    constexpr int ACH = BM * 4;   // 16B chunks in A tile
    constexpr int BCH = BN * 4;

    for (int k0 = 0; k0 < K; k0 += 32) {
#pragma unroll
        for (int i = 0; i < (ACH + 255) / 256; ++i) {
            int c = i * 256 + tid;
            if (ACH % 256 == 0 || c < ACH) {
                int row = c >> 2, ck = c & 3;
                int kk = k0 + ck * 8;
                const unsigned short* gp = (kk < KS)
                    ? A  + (size_t)(m0 + row) * lda  + kk
                    : A2 + (size_t)(m0 + row) * lda2 + (kk - KS);
                gload_lds16(gp, As + (size_t)(i * 256 + wave * 64) * 8);
            }
        }
#pragma unroll
        for (int i = 0; i < (BCH + 255) / 256; ++i) {
            int c = i * 256 + tid;
            if (BCH % 256 == 0 || c < BCH) {
                int row = c >> 2, ck = c & 3;
                gload_lds16(Bt + (size_t)(n0 + row) * ldb + k0 + ck * 8,
                            Bs + (size_t)(i * 256 + wave * 64) * 8);
            }
        }
        __syncthreads();
        bh8 av[FM], bv[FN];
#pragma unroll
        for (int mi = 0; mi < FM; ++mi)
            av[mi] = *(const bh8*)((const char*)As + (((wr * FM + mi) * 16 + l16) * 64 + kh * 16));
#pragma unroll
        for (int ni = 0; ni < FN; ++ni)
            bv[ni] = *(const bh8*)((const char*)Bs + (((wc * FN + ni) * 16 + l16) * 64 + kh * 16));
#pragma unroll
        for (int mi = 0; mi < FM; ++mi)
#pragma unroll
            for (int ni = 0; ni < FN; ++ni)
                acc[mi][ni] = __builtin_amdgcn_mfma_f32_16x16x32_bf16(
                    av[mi], bv[ni], acc[mi][ni], 0, 0, 0);
        __syncthreads();
    }

#pragma unroll
    for (int mi = 0; mi < FM; ++mi) {
#pragma unroll
        for (int ni = 0; ni < FN; ++ni) {
            int col = n0 + (wc * FN + ni) * 16 + l16;
            float bcol = HAS_BIAS ? bias[col] : 0.f;
#pragma unroll
            for (int j = 0; j < 4; ++j) {
                int row = m0 + (wr * FM + mi) * 16 + kh * 4 + j;
                float v = acc[mi][ni][j] + bcol;
                if (ACT == 1) v = v * (1.f / (1.f + __expf(-v)));
                else if (ACT == 2) v = tanhf(v);
                if (ZPAD) {
                    int br = col >> 5, cc = col & 31;
                    unsigned short* zp = (unsigned short*)outp
                        + (size_t)br * NTH64 + (size_t)row * 64 + cc;
                    zp[0] = f2bf(v);
                    zp[32] = 0;
                } else if (OF32) {
                    ((float*)outp)[(size_t)row * ldo + col] = v;
                } else {
                    ((unsigned short*)outp)[(size_t)row * ldo + col] = f2bf(v);
                }
            }
        }
    }
}

// ============ 8-phase pipelined bigproj: 128x256 tile, BK=64, 512 thr ======
// 3-buffer LDS (A 16KB + B 32KB per buf = 144KB), prefetch distance 2 K-tiles,
// counted vmcnt(6) at K-tile boundaries, st_16x32 LDS swizzle (both-sides).
__global__ __launch_bounds__(512, 2) void bigproj8_kernel(
    const unsigned short* __restrict__ A,      // shifted [NROWS][2048]
    const unsigned short* __restrict__ zpad,   // [5][NROWS][64] (cols 32..63 = 0)
    const unsigned short* __restrict__ bt0, const unsigned short* __restrict__ bt1,
    const unsigned short* __restrict__ bt2, const unsigned short* __restrict__ bt3,
    const float* __restrict__ bias4, float* __restrict__ out) {
    constexpr int BUFB = 49152;          // bytes per K-tile buffer
    constexpr int NTK = KC8 / 64;        // 33 K-tiles
    __shared__ alignas(16) char lds[3 * BUFB];

    const int bid = blockIdx.x;                      // 4096 blocks
    const int swz = (bid & 7) * 512 + (bid >> 3);    // bijective XCD swizzle
    const int branch = swz >> 10;                    // 0..3 = R,K,V,G
    const int tile = swz & 1023;
    const int m0 = (tile >> 3) * 128, n0 = (tile & 7) * 256;

    const unsigned short* Bt = branch == 0 ? bt0 : branch == 1 ? bt1
                             : branch == 2 ? bt2 : bt3;
    const int f = (0x4213 >> (branch * 4)) & 15;     // fidx {3,1,2,4}
    const unsigned short* Az = zpad + (size_t)f * NTH64;

    const int tid = threadIdx.x;
    const int wave = tid >> 6, lane = tid & 63;
    const int l16 = lane & 15, kh = lane >> 4;
    const int wm = wave >> 2, wn = wave & 3;         // 2M x 4N waves
    const int kh16 = kh * 16;
    const int swr = (l16 & 8) << 2;                  // read-side XOR (st_16x32)

    // stage one K-tile's A half (2 rounds) -- source pre-swizzled, dest linear
    auto stageA = [&](int kt, char* nb) {
#pragma unroll
        for (int j = 0; j < 2; ++j) {
            int c = j * 512 + wave * 64 + lane;      // chunk 0..1023
            int mf = c >> 7;                          // subtile m-frag
            int kk = (c >> 6) & 1;
            int lr = (c >> 2) & 15;
            int kbx = ((c & 3) * 16) ^ ((lr & 8) << 2);
            int ke = kt * 64 + kk * 32 + (kbx >> 1);
            int row = m0 + mf * 16 + lr;
            const unsigned short* gp = (ke < 2048)
                ? A  + (size_t)row * 2048 + ke
                : Az + (size_t)row * 64 + (ke - 2048);
            gload_lds16(gp, nb + (size_t)(j * 512 + wave * 64) * 16);
        }
    };
    auto stageB = [&](int kt, char* nb, int j0) {     // 2 of 4 B rounds
#pragma unroll
        for (int jj = 0; jj < 2; ++jj) {
            int j = j0 + jj;
            int c = j * 512 + wave * 64 + lane;      // chunk 0..2047
            int nf = c >> 7;
            int kk = (c >> 6) & 1;
            int lr = (c >> 2) & 15;
            int kbx = ((c & 3) * 16) ^ ((lr & 8) << 2);
            int ke = kt * 64 + kk * 32 + (kbx >> 1);
            int rown = n0 + nf * 16 + lr;
            gload_lds16(Bt + (size_t)rown * KC8 + ke,
                        nb + 16384 + (size_t)(j * 512 + wave * 64) * 16);
        }
    };

    f32x4 acc[4][4] = {};

    // prologue: stage tiles 0 and 1 (6 loads each)
    stageA(0, lds);            stageB(0, lds, 0);            stageB(0, lds, 2);
    stageA(1, lds + BUFB);     stageB(1, lds + BUFB, 0);     stageB(1, lds + BUFB, 2);
    asm volatile("s_waitcnt vmcnt(6)" ::: "memory");   // tile 0 complete
    __builtin_amdgcn_s_barrier();
    __builtin_amdgcn_sched_barrier(0);

    for (int t = 0; t < NTK; ++t) {
        const char* buf = lds + (t % 3) * BUFB;
        char* nbuf = lds + ((t + 2) % 3) * BUFB;
        const bool doSt = (t + 2) < NTK;
#pragma unroll
        for (int p = 0; p < 4; ++p) {
            const int ms = p >> 1, ns = p & 1;
            bh8 av[2][2], bv[2][2];
#pragma unroll
            for (int mi = 0; mi < 2; ++mi)
#pragma unroll
                for (int kk = 0; kk < 2; ++kk)
                    av[mi][kk] = *(const bh8*)(buf
                        + ((wm * 4 + ms * 2 + mi) * 2 + kk) * 1024
                        + l16 * 64 + (kh16 ^ swr));
#pragma unroll
            for (int ni = 0; ni < 2; ++ni)
#pragma unroll
                for (int kk = 0; kk < 2; ++kk)
                    bv[ni][kk] = *(const bh8*)(buf + 16384
                        + ((wn * 4 + ns * 2 + ni) * 2 + kk) * 1024
                        + l16 * 64 + (kh16 ^ swr));
            if (doSt) {
                if (p == 0)      stageA(t + 2, nbuf);
                else if (p == 1) stageB(t + 2, nbuf, 0);
                else if (p == 2) stageB(t + 2, nbuf, 2);
            }
            __builtin_amdgcn_s_barrier();
            __builtin_amdgcn_s_setprio(1);
#pragma unroll
            for (int mi = 0; mi < 2; ++mi)
#pragma unroll
                for (int ni = 0; ni < 2; ++ni)
#pragma unroll
                    for (int kk = 0; kk < 2; ++kk)
                        acc[ms * 2 + mi][ns * 2 + ni] =
                            __builtin_amdgcn_mfma_f32_16x16x32_bf16(
                                av[mi][kk], bv[ni][kk],
                                acc[ms * 2 + mi][ns * 2 + ni], 0, 0, 0);
            __builtin_amdgcn_s_setprio(0);
            __builtin_amdgcn_s_barrier();
        }
        // K-tile boundary: ensure tile t+1 resident; leave tile t+2's 6 in flight
        if (t < NTK - 2) asm volatile("s_waitcnt vmcnt(6)" ::: "memory");
        else             asm volatile("s_waitcnt vmcnt(0)" ::: "memory");
        __builtin_amdgcn_s_barrier();
        __builtin_amdgcn_sched_barrier(0);
    }

    float* outp = out + (size_t)branch * NTH;
    const float* bias = bias4 + branch * H;
#pragma unroll
    for (int a = 0; a < 4; ++a) {
#pragma unroll
        for (int b = 0; b < 4; ++b) {
            int col = n0 + wn * 64 + b * 16 + l16;
            float bc = bias[col];
#pragma unroll
            for (int j = 0; j < 4; ++j) {
                int row = m0 + wm * 64 + a * 16 + kh * 4 + j;
                float v = acc[a][b][j] + bc;
                if (branch == 3) v = v * (1.f / (1.f + __expf(-v)));   // silu
                outp[(size_t)row * H + col] = v;
            }
        }
    }
}

// ------- td stage 2 (fp32 VALU): out = tdecay + tdmid(N x 64) @ W2d(64 x H) ----
__global__ __launch_bounds__(256) void td2_kernel(
    const float* __restrict__ tdmid, const float* __restrict__ W2d,
    const float* __restrict__ tdecay, float* __restrict__ outp) {
    int col = blockIdx.x * 256 + threadIdx.x;
    int row0 = blockIdx.y * 8;
    float a[8] = {0, 0, 0, 0, 0, 0, 0, 0};
    for (int r = 0; r < 64; ++r) {
        float w = W2d[(size_t)r * H + col];
#pragma unroll
        for (int j = 0; j < 8; ++j)
            a[j] += tdmid[(size_t)(row0 + j) * 64 + r] * w;
    }
    float b = tdecay[col];
#pragma unroll
    for (int j = 0; j < 8; ++j)
        outp[(size_t)(row0 + j) * H + col] = a[j] + b;
}

// ---------------- attn_x_new = hidden[:, -1]  (fp32, exact) ---------------
__global__ __launch_bounds__(256) void axnew_kernel(
    const float* __restrict__ hidden, float* __restrict__ outp) {
    int i = blockIdx.x * 256 + threadIdx.x;       // 0..8191
    int b = i >> 11, h = i & 2047;
    outp[i] = hidden[((size_t)(b * TT + (TT - 1)) << 11) + h];
}

extern "C" void kernel_launch(void* const* d_in, const int* in_sizes, int n_in,
                              void* d_out, int out_size, void* d_ws, size_t ws_size,
                              hipStream_t stream) {
    const float* hidden = (const float*)d_in[0];
    const float* attn_x = (const float*)d_in[1];
    const float* tmx    = (const float*)d_in[4];
    const float* tmaa_w = (const float*)d_in[5];
    const float* tmaa_k = (const float*)d_in[6];
    const float* tmaa_v = (const float*)d_in[7];
    const float* tmaa_r = (const float*)d_in[8];
    const float* tmaa_g = (const float*)d_in[9];
    const float* W1     = (const float*)d_in[10];   // (H,160)
    const float* W2     = (const float*)d_in[11];   // (5,32,H)
    const float* tdecay = (const float*)d_in[12];   // (1,1,H)
    const float* W1d    = (const float*)d_in[13];   // (H,64)
    const float* W2d    = (const float*)d_in[14];   // (64,H)
    const float* Wr     = (const float*)d_in[16];
    const float* Wk     = (const float*)d_in[17];
    const float* Wv     = (const float*)d_in[18];
    const float* Wg     = (const float*)d_in[19];

    float* out = (float*)d_out;     // reference outputs are float32

    char* ws = (char*)d_ws;
    size_t off = 0;
    auto alloc = [&](size_t bytes) {
        char* p = ws + off;
        off = (off + bytes + 255) & ~(size_t)255;
        return p;
    };
    unsigned short* shifted = (unsigned short*)alloc(NTH * 2);
    unsigned short* xin     = (unsigned short*)alloc(NTH * 2);
    unsigned short* zpad    = (unsigned short*)alloc(5 * NTH64 * 2);
    unsigned short* W1t     = (unsigned short*)alloc((size_t)160 * H * 2);
    unsigned short* BcatR   = (unsigned short*)alloc((size_t)H * KC8 * 2);
    unsigned short* BcatK   = (unsigned short*)alloc((size_t)H * KC8 * 2);
    unsigned short* BcatV   = (unsigned short*)alloc((size_t)H * KC8 * 2);
    unsigned short* BcatG   = (unsigned short*)alloc((size_t)H * KC8 * 2);
    unsigned short* Bcat1   = (unsigned short*)alloc((size_t)64 * KCAT * 2);
    float* tdmid            = (float*)alloc((size_t)NROWS * 64 * 4);
    float* bias4            = (float*)alloc(4 * H * 4);
    float* bias0            = (float*)alloc(64 * 4);

    // 1. shifted / xin
    prep_kernel<<<(unsigned)(NTH / (4 * 256)), 256, 0, stream>>>(hidden, attn_x, tmx, shifted, xin);

    // 2. fused weights: transposes + low-rank fusion + biases
    transpose4_kernel<<<dim3(64, 64, 4), 256, 0, stream>>>(
        Wr, Wk, Wv, Wg, BcatR, BcatK, BcatV, BcatG);
    transpose_kernel<<<dim3(5, 64), 256, 0, stream>>>(W1, W1t, H, 160, H);
    transpose_kernel<<<dim3(2, 64), 256, 0, stream>>>(W1d, Bcat1, H, 64, KCAT);
    w2w4_kernel<<<dim3(8, 4, 4), 256, 0, stream>>>(
        W2, Wr, Wk, Wv, Wg, BcatR, BcatK, BcatV, BcatG);
    w2w_kernel<<<dim3(1, 4), 256, 0, stream>>>(W2, W1d, 64, Bcat1, KCAT);
    bias_all_kernel<<<2064, 256, 0, stream>>>(
        BcatR, BcatK, BcatV, BcatG, Bcat1,
        tmaa_r, tmaa_k, tmaa_v, tmaa_g, tmaa_w, bias4, bias0);

    // 3. z = tanh(xin @ W1) -> zpad [5][NROWS][64], cols 32..63 zeroed
    gemm_kernel<4, 1, 2, 10, 0, 2, 0, 1><<<128, 256, 0, stream>>>(
        xin, H, xin, H, H, W1t, H, H, zpad, 0, 1, nullptr);

    // 4. big projections (merged R,K,V,G), 8-phase pipelined
    bigproj8_kernel<<<4096, 512, 0, stream>>>(
        shifted, zpad, BcatR, BcatK, BcatV, BcatG, bias4, out);

    // 5. decay: tdmid = tanh([shifted | z_0] @ Bcat1^T + bias0)   (fp32 out)
    gemm_kernel<4, 1, 1, 4, 1, 2, 1, 0><<<256, 256, 0, stream>>>(
        shifted, H, zpad, 64, H, Bcat1, KCAT, KCAT,
        tdmid, 64, 1, bias0);
    //    td = time_decay + tdmid @ W2d   (fp32 VALU, register-blocked)
    td2_kernel<<<dim3(8, NROWS / 8), 256, 0, stream>>>(
        tdmid, W2d, tdecay, out + 4 * NTH);

    // 6. attn_x_new (exact fp32 copy)
    axnew_kernel<<<32, 256, 0, stream>>>(hidden, out + 5 * NTH);
}

// Round 6
// 1122.581 us; speedup vs baseline: 2.3004x; 1.1610x over previous
//
#include <hip/hip_runtime.h>

#define H 2048
#define TT 4096
#define BB 4
#define NROWS (BB * TT)               // 16384
#define NTH ((size_t)NROWS * H)       // 33,554,432
#define KCAT (H + 32)                 // 2080 (decay path)
#define KC8  (H + 64)                 // 2112 (bigproj, zero-padded)
#define NTH64 ((size_t)NROWS * 64)

typedef __attribute__((ext_vector_type(8))) short bh8;
typedef __attribute__((ext_vector_type(4))) float f32x4;

__device__ inline unsigned short f2bf(float f) {
    union { float f; unsigned u; } v; v.f = f;
    unsigned r = v.u + 0x7fff + ((v.u >> 16) & 1);   // RNE
    return (unsigned short)(r >> 16);
}
__device__ inline float bf2f(unsigned short u) {
    union { unsigned u; float f; } v; v.u = ((unsigned)u) << 16; return v.f;
}
__device__ inline void gload_lds16(const void* g, void* l) {
    __builtin_amdgcn_global_load_lds(
        (const __attribute__((address_space(1))) void*)g,
        (__attribute__((address_space(3))) void*)l, 16, 0, 0);
}

// ---------------- prep: shifted & xin (bf16), vectorized ----------------
__global__ __launch_bounds__(256) void prep_kernel(
    const float* __restrict__ hidden, const float* __restrict__ attn_x,
    const float* __restrict__ tmx,
    unsigned short* __restrict__ shifted, unsigned short* __restrict__ xin) {
    size_t i = ((size_t)blockIdx.x * 256 + threadIdx.x) * 4;
    int n = (int)(i >> 11);
    int h = (int)(i & 2047);
    int t = n & (TT - 1);
    float4 x = *(const float4*)(hidden + i);
    float4 s;
    if (t == 0) {
        int b = n >> 12;
        s = *(const float4*)(attn_x + ((size_t)b << 11) + h);
    } else {
        s = *(const float4*)(hidden + (i - H));
    }
    float4 m = *(const float4*)(tmx + h);
    ushort4 sh, xi;
    sh.x = f2bf(s.x); sh.y = f2bf(s.y); sh.z = f2bf(s.z); sh.w = f2bf(s.w);
    xi.x = f2bf(x.x + (s.x - x.x) * m.x);
    xi.y = f2bf(x.y + (s.y - x.y) * m.y);
    xi.z = f2bf(x.z + (s.z - x.z) * m.z);
    xi.w = f2bf(x.w + (s.w - x.w) * m.w);
    *(ushort4*)(shifted + i) = sh;
    *(ushort4*)(xin + i) = xi;
}

// ---------------- transpose fp32 (R x C) -> bf16 (C x R), out ld = ldo ----
__global__ __launch_bounds__(256) void transpose_kernel(
    const float* __restrict__ in, unsigned short* __restrict__ outp,
    int R, int C, int ldo) {
    __shared__ float tile[32][33];
    int tx = threadIdx.x & 31, ty = threadIdx.x >> 5;
    int r0 = blockIdx.y * 32, c0 = blockIdx.x * 32;
    for (int i = ty; i < 32; i += 8) {
        int r = r0 + i, c = c0 + tx;
        tile[i][tx] = (r < R && c < C) ? in[(size_t)r * C + c] : 0.f;
    }
    __syncthreads();
    for (int i = ty; i < 32; i += 8) {
        int c = c0 + i, r = r0 + tx;
        if (c < C && r < R) outp[(size_t)c * ldo + r] = f2bf(tile[tx][i]);
    }
}

// ---------------- merged transpose of the 4 big weights (H x H, ldo=KC8) --
__global__ __launch_bounds__(256) void transpose4_kernel(
    const float* __restrict__ w0, const float* __restrict__ w1,
    const float* __restrict__ w2, const float* __restrict__ w3,
    unsigned short* __restrict__ d0, unsigned short* __restrict__ d1,
    unsigned short* __restrict__ d2, unsigned short* __restrict__ d3) {
    __shared__ float tile[32][33];
    int bz = blockIdx.z;
    const float* in = bz == 0 ? w0 : bz == 1 ? w1 : bz == 2 ? w2 : w3;
    unsigned short* outp = bz == 0 ? d0 : bz == 1 ? d1 : bz == 2 ? d2 : d3;
    int tx = threadIdx.x & 31, ty = threadIdx.x >> 5;
    int r0 = blockIdx.y * 32, c0 = blockIdx.x * 32;
    for (int i = ty; i < 32; i += 8)
        tile[i][tx] = in[(size_t)(r0 + i) * H + c0 + tx];
    __syncthreads();
    for (int i = ty; i < 32; i += 8)
        outp[(size_t)(c0 + i) * KC8 + r0 + tx] = f2bf(tile[tx][i]);
}

// ------ merged W2W for 4 branches: cols [H..H+32) of Bcat, zeros [H+32..H+64) -
__global__ __launch_bounds__(256) void w2w4_kernel(
    const float* __restrict__ W2,
    const float* __restrict__ w0, const float* __restrict__ w1,
    const float* __restrict__ w2, const float* __restrict__ w3,
    unsigned short* __restrict__ d0, unsigned short* __restrict__ d1,
    unsigned short* __restrict__ d2, unsigned short* __restrict__ d3) {
    __shared__ float lds[8 * H];
    int bz = blockIdx.z;
    const float* W = bz == 0 ? w0 : bz == 1 ? w1 : bz == 2 ? w2 : w3;
    unsigned short* dst = bz == 0 ? d0 : bz == 1 ? d1 : bz == 2 ? d2 : d3;
    const float* W2f = W2 + (size_t)((0x4213 >> (bz * 4)) & 15) * 32 * H;
    const int tid = threadIdx.x;
    const int rg = blockIdx.y;             // group of 8 r's
    for (int i = tid; i < 8 * H; i += 256) lds[i] = W2f[(size_t)rg * 8 * H + i];
    __syncthreads();
    int d = blockIdx.x * 256 + tid;
    float a[8] = {0, 0, 0, 0, 0, 0, 0, 0};
    for (int hh = 0; hh < H; ++hh) {
        float w = W[(size_t)hh * H + d];
#pragma unroll
        for (int r = 0; r < 8; ++r) a[r] += lds[r * H + hh] * w;
    }
#pragma unroll
    for (int r = 0; r < 8; ++r) {
        dst[(size_t)d * KC8 + H + rg * 8 + r] = f2bf(a[r]);
        dst[(size_t)d * KC8 + H + 32 + rg * 8 + r] = 0;   // zero pad
    }
}

// ------------- W2W single (decay): (32 x H) @ (H x 64) -> Bcat1 cols [H..H+32) -
__global__ __launch_bounds__(256) void w2w_kernel(
    const float* __restrict__ W2f, const float* __restrict__ W, int D,
    unsigned short* __restrict__ dst, int ldb) {
    __shared__ float lds[8 * H];
    const int tid = threadIdx.x;
    const int rg = blockIdx.y;
    for (int i = tid; i < 8 * H; i += 256) lds[i] = W2f[(size_t)rg * 8 * H + i];
    __syncthreads();
    int d = blockIdx.x * 256 + tid;
    if (d >= D) return;
    float a[8] = {0, 0, 0, 0, 0, 0, 0, 0};
    for (int hh = 0; hh < H; ++hh) {
        float w = W[(size_t)hh * D + d];
#pragma unroll
        for (int r = 0; r < 8; ++r) a[r] += lds[r * H + hh] * w;
    }
#pragma unroll
    for (int r = 0; r < 8; ++r)
        dst[(size_t)d * ldb + H + rg * 8 + r] = f2bf(a[r]);
}

// -------- bias (merged): wave per row; bias[d] = dot(maa, W[:,d]) via Bcat rows --
__global__ __launch_bounds__(256) void bias_all_kernel(
    const unsigned short* __restrict__ bR, const unsigned short* __restrict__ bK,
    const unsigned short* __restrict__ bV, const unsigned short* __restrict__ bG,
    const unsigned short* __restrict__ b1,
    const float* __restrict__ mR, const float* __restrict__ mK,
    const float* __restrict__ mV, const float* __restrict__ mG,
    const float* __restrict__ mW,
    float* __restrict__ bias4, float* __restrict__ bias0) {
    int wave = threadIdx.x >> 6, lane = threadIdx.x & 63;
    int p = blockIdx.x * 4 + wave;          // 0..8255
    const unsigned short* src; const float* maa; float* dst;
    if (p < 8192) {
        int br = p >> 11, row = p & 2047;
        src = (br == 0 ? bR : br == 1 ? bK : br == 2 ? bV : bG) + (size_t)row * KC8;
        maa = (br == 0 ? mR : br == 1 ? mK : br == 2 ? mV : mG);
        dst = bias4 + br * H + row;
    } else {
        int q = p - 8192;
        if (q >= 64) return;
        src = b1 + (size_t)q * KCAT; maa = mW; dst = bias0 + q;
    }
    float a = 0.f;
#pragma unroll 4
    for (int i = 0; i < 32; ++i) { int h = i * 64 + lane; a += bf2f(src[h]) * maa[h]; }
    for (int s = 32; s; s >>= 1) a += __shfl_xor(a, s);
    if (lane == 0) *dst = a;
}

// ---------------- old-style MFMA GEMM core (z / tdmid) --------------------
template <int WM, int WN, int FM, int FN, int HAS_BIAS, int ACT, int OF32, int ZPAD>
__global__ __launch_bounds__(256) void gemm_kernel(
    const unsigned short* __restrict__ A, int lda,
    const unsigned short* __restrict__ A2, int lda2, int KS,
    const unsigned short* __restrict__ Bt, int ldb, int K,
    void* __restrict__ outp, int ldo, int NT,
    const float* __restrict__ bias) {
    static_assert(WM * WN == 4, "4 waves");
    constexpr int BM = WM * FM * 16;
    constexpr int BN = WN * FN * 16;
    __shared__ unsigned short As[BM * 32];
    __shared__ unsigned short Bs[BN * 32];

    const int nb = gridDim.x;
    const int bid = blockIdx.x;
    const int swz = (bid & 7) * (nb >> 3) + (bid >> 3);   // nb % 8 == 0
    const int mt = swz / NT, nt = swz % NT;
    const int m0 = mt * BM, n0 = nt * BN;

    const int tid = threadIdx.x;
    const int wave = tid >> 6, lane = tid & 63;
    const int l16 = lane & 15, kh = lane >> 4;
    const int wr = wave / WN, wc = wave % WN;

    f32x4 acc[FM][FN] = {};

    constexpr int ACH = BM * 4;   // 16B chunks in A tile
    constexpr int BCH = BN * 4;

    for (int k0 = 0; k0 < K; k0 += 32) {
#pragma unroll
        for (int i = 0; i < (ACH + 255) / 256; ++i) {
            int c = i * 256 + tid;
            if (ACH % 256 == 0 || c < ACH) {
                int row = c >> 2, ck = c & 3;
                int kk = k0 + ck * 8;
                const unsigned short* gp = (kk < KS)
                    ? A  + (size_t)(m0 + row) * lda  + kk
                    : A2 + (size_t)(m0 + row) * lda2 + (kk - KS);
                gload_lds16(gp, As + (size_t)(i * 256 + wave * 64) * 8);
            }
        }
#pragma unroll
        for (int i = 0; i < (BCH + 255) / 256; ++i) {
            int c = i * 256 + tid;
            if (BCH % 256 == 0 || c < BCH) {
                int row = c >> 2, ck = c & 3;
                gload_lds16(Bt + (size_t)(n0 + row) * ldb + k0 + ck * 8,
                            Bs + (size_t)(i * 256 + wave * 64) * 8);
            }
        }
        __syncthreads();
        bh8 av[FM], bv[FN];
#pragma unroll
        for (int mi = 0; mi < FM; ++mi)
            av[mi] = *(const bh8*)((const char*)As + (((wr * FM + mi) * 16 + l16) * 64 + kh * 16));
#pragma unroll
        for (int ni = 0; ni < FN; ++ni)
            bv[ni] = *(const bh8*)((const char*)Bs + (((wc * FN + ni) * 16 + l16) * 64 + kh * 16));
#pragma unroll
        for (int mi = 0; mi < FM; ++mi)
#pragma unroll
            for (int ni = 0; ni < FN; ++ni)
                acc[mi][ni] = __builtin_amdgcn_mfma_f32_16x16x32_bf16(
                    av[mi], bv[ni], acc[mi][ni], 0, 0, 0);
        __syncthreads();
    }

#pragma unroll
    for (int mi = 0; mi < FM; ++mi) {
#pragma unroll
        for (int ni = 0; ni < FN; ++ni) {
            int col = n0 + (wc * FN + ni) * 16 + l16;
            float bcol = HAS_BIAS ? bias[col] : 0.f;
#pragma unroll
            for (int j = 0; j < 4; ++j) {
                int row = m0 + (wr * FM + mi) * 16 + kh * 4 + j;
                float v = acc[mi][ni][j] + bcol;
                if (ACT == 1) v = v * (1.f / (1.f + __expf(-v)));
                else if (ACT == 2) v = tanhf(v);
                if (ZPAD) {
                    int br = col >> 5, cc = col & 31;
                    unsigned short* zp = (unsigned short*)outp
                        + (size_t)br * NTH64 + (size_t)row * 64 + cc;
                    zp[0] = f2bf(v);
                    zp[32] = 0;
                } else if (OF32) {
                    ((float*)outp)[(size_t)row * ldo + col] = v;
                } else {
                    ((unsigned short*)outp)[(size_t)row * ldo + col] = f2bf(v);
                }
            }
        }
    }
}

// ====== bigproj: 256x256 tile, BK=32, 8 waves (2Mx4N), per-wave 128x64 =====
// 4-deep LDS ring (4 x 32KB = 128KB), prefetch distance 2 K-tiles,
// steady-state vmcnt(4), st_16x32 swizzle (source+read), bv held across phases.
__global__ __launch_bounds__(512, 2) void bigproj8_kernel(
    const unsigned short* __restrict__ A,      // shifted [NROWS][2048]
    const unsigned short* __restrict__ zpad,   // [5][NROWS][64] (cols 32..63 = 0)
    const unsigned short* __restrict__ bt0, const unsigned short* __restrict__ bt1,
    const unsigned short* __restrict__ bt2, const unsigned short* __restrict__ bt3,
    const float* __restrict__ bias4, float* __restrict__ out) {
    constexpr int BUFB = 32768;          // bytes per K-tile buffer (A 16K + B 16K)
    constexpr int NTK = KC8 / 32;        // 66 K-tiles
    __shared__ alignas(16) char lds[4 * BUFB];

    const int bid = blockIdx.x;                      // 2048 blocks
    const int swz = (bid & 7) * 256 + (bid >> 3);    // bijective XCD swizzle
    const int branch = swz >> 9;                     // 0..3 = R,K,V,G
    const int tile = swz & 511;
    const int m0 = (tile >> 3) * 256, n0 = (tile & 7) * 256;

    const unsigned short* Bt = branch == 0 ? bt0 : branch == 1 ? bt1
                             : branch == 2 ? bt2 : bt3;
    const int f = (0x4213 >> (branch * 4)) & 15;     // fidx {3,1,2,4}
    const unsigned short* Az = zpad + (size_t)f * NTH64;

    const int tid = threadIdx.x;
    const int wave = tid >> 6, lane = tid & 63;
    const int l16 = lane & 15, kh = lane >> 4;
    const int wm = wave >> 2, wn = wave & 3;         // 2M x 4N waves
    const int kh16 = kh * 16;
    const int swr = (l16 & 8) << 2;                  // read-side XOR (st_16x32)

    // stage A half of K-tile kt (2 rounds, 1 gload/thread each)
    auto stageA = [&](int kt, char* nb) {
#pragma unroll
        for (int j = 0; j < 2; ++j) {
            int c = j * 512 + tid;                   // 0..1023
            int r = c >> 2, ck = c & 3;
            int kbx = (ck * 16) ^ ((r & 8) << 2);    // byte offset in 64B k-line
            int ke = kt * 32 + (kbx >> 1);
            int row = m0 + r;
            const unsigned short* gp = (ke < 2048)
                ? A  + (size_t)row * 2048 + ke
                : Az + (size_t)row * 64 + (ke - 2048);
            gload_lds16(gp, nb + (size_t)(j * 512 + wave * 64) * 16);
        }
    };
    auto stageB = [&](int kt, char* nb) {
#pragma unroll
        for (int j = 0; j < 2; ++j) {
            int c = j * 512 + tid;
            int r = c >> 2, ck = c & 3;
            int kbx = (ck * 16) ^ ((r & 8) << 2);
            int ke = kt * 32 + (kbx >> 1);
            gload_lds16(Bt + (size_t)(n0 + r) * KC8 + ke,
                        nb + 16384 + (size_t)(j * 512 + wave * 64) * 16);
        }
    };

    f32x4 acc[8][4] = {};

    // prologue: stage K-tiles 0 and 1 (4 rounds each)
    stageA(0, lds);        stageB(0, lds);
    stageA(1, lds + BUFB); stageB(1, lds + BUFB);
    asm volatile("s_waitcnt vmcnt(4)" ::: "memory");   // tile 0 complete
    __builtin_amdgcn_s_barrier();
    __builtin_amdgcn_sched_barrier(0);

    for (int t = 0; t < NTK; ++t) {
        const char* Ab = lds + (t & 3) * BUFB;
        const char* Bb = Ab + 16384;
        char* nb = lds + ((t + 2) & 3) * BUFB;
        const bool doSt = (t + 2) < NTK;

        // ---- phase 0: m-frags 0..3, load bv for whole K-tile ----
        bh8 av[4], bv[4];
#pragma unroll
        for (int i = 0; i < 4; ++i)
            av[i] = *(const bh8*)(Ab + (wm * 8 + i) * 1024 + l16 * 64 + (kh16 ^ swr));
#pragma unroll
        for (int i = 0; i < 4; ++i)
            bv[i] = *(const bh8*)(Bb + (wn * 4 + i) * 1024 + l16 * 64 + (kh16 ^ swr));
        if (doSt) stageA(t + 2, nb);
        __builtin_amdgcn_s_barrier();
        __builtin_amdgcn_s_setprio(1);
#pragma unroll
        for (int mi = 0; mi < 4; ++mi)
#pragma unroll
            for (int ni = 0; ni < 4; ++ni)
                acc[mi][ni] = __builtin_amdgcn_mfma_f32_16x16x32_bf16(
                    av[mi], bv[ni], acc[mi][ni], 0, 0, 0);
        __builtin_amdgcn_s_setprio(0);
        __builtin_amdgcn_s_barrier();

        // ---- phase 1: m-frags 4..7 (bv reused from registers) ----
        bh8 av2[4];
#pragma unroll
        for (int i = 0; i < 4; ++i)
            av2[i] = *(const bh8*)(Ab + (wm * 8 + 4 + i) * 1024 + l16 * 64 + (kh16 ^ swr));
        if (doSt) stageB(t + 2, nb);
        // boundary: tile t+1 complete; tile t+2's 4 rounds stay in flight
        if (doSt) asm volatile("s_waitcnt vmcnt(4)" ::: "memory");
        else      asm volatile("s_waitcnt vmcnt(0)" ::: "memory");
        __builtin_amdgcn_s_barrier();
        __builtin_amdgcn_sched_barrier(0);
        __builtin_amdgcn_s_setprio(1);
#pragma unroll
        for (int mi = 0; mi < 4; ++mi)
#pragma unroll
            for (int ni = 0; ni < 4; ++ni)
                acc[4 + mi][ni] = __builtin_amdgcn_mfma_f32_16x16x32_bf16(
                    av2[mi], bv[ni], acc[4 + mi][ni], 0, 0, 0);
        __builtin_amdgcn_s_setprio(0);
        __builtin_amdgcn_s_barrier();
    }

    float* outp = out + (size_t)branch * NTH;
    const float* bias = bias4 + branch * H;
#pragma unroll
    for (int a = 0; a < 8; ++a) {
#pragma unroll
        for (int b = 0; b < 4; ++b) {
            int col = n0 + wn * 64 + b * 16 + l16;
            float bc = bias[col];
#pragma unroll
            for (int j = 0; j < 4; ++j) {
                int row = m0 + wm * 128 + a * 16 + kh * 4 + j;
                float v = acc[a][b][j] + bc;
                if (branch == 3) v = v * (1.f / (1.f + __expf(-v)));   // silu
                outp[(size_t)row * H + col] = v;
            }
        }
    }
}

// ------- td stage 2 (fp32 VALU): out = tdecay + tdmid(N x 64) @ W2d(64 x H) ----
__global__ __launch_bounds__(256) void td2_kernel(
    const float* __restrict__ tdmid, const float* __restrict__ W2d,
    const float* __restrict__ tdecay, float* __restrict__ outp) {
    int col = blockIdx.x * 256 + threadIdx.x;
    int row0 = blockIdx.y * 8;
    float a[8] = {0, 0, 0, 0, 0, 0, 0, 0};
    for (int r = 0; r < 64; ++r) {
        float w = W2d[(size_t)r * H + col];
#pragma unroll
        for (int j = 0; j < 8; ++j)
            a[j] += tdmid[(size_t)(row0 + j) * 64 + r] * w;
    }
    float b = tdecay[col];
#pragma unroll
    for (int j = 0; j < 8; ++j)
        outp[(size_t)(row0 + j) * H + col] = a[j] + b;
}

// ---------------- attn_x_new = hidden[:, -1]  (fp32, exact) ---------------
__global__ __launch_bounds__(256) void axnew_kernel(
    const float* __restrict__ hidden, float* __restrict__ outp) {
    int i = blockIdx.x * 256 + threadIdx.x;       // 0..8191
    int b = i >> 11, h = i & 2047;
    outp[i] = hidden[((size_t)(b * TT + (TT - 1)) << 11) + h];
}

extern "C" void kernel_launch(void* const* d_in, const int* in_sizes, int n_in,
                              void* d_out, int out_size, void* d_ws, size_t ws_size,
                              hipStream_t stream) {
    const float* hidden = (const float*)d_in[0];
    const float* attn_x = (const float*)d_in[1];
    const float* tmx    = (const float*)d_in[4];
    const float* tmaa_w = (const float*)d_in[5];
    const float* tmaa_k = (const float*)d_in[6];
    const float* tmaa_v = (const float*)d_in[7];
    const float* tmaa_r = (const float*)d_in[8];
    const float* tmaa_g = (const float*)d_in[9];
    const float* W1     = (const float*)d_in[10];   // (H,160)
    const float* W2     = (const float*)d_in[11];   // (5,32,H)
    const float* tdecay = (const float*)d_in[12];   // (1,1,H)
    const float* W1d    = (const float*)d_in[13];   // (H,64)
    const float* W2d    = (const float*)d_in[14];   // (64,H)
    const float* Wr     = (const float*)d_in[16];
    const float* Wk     = (const float*)d_in[17];
    const float* Wv     = (const float*)d_in[18];
    const float* Wg     = (const float*)d_in[19];

    float* out = (float*)d_out;     // reference outputs are float32

    char* ws = (char*)d_ws;
    size_t off = 0;
    auto alloc = [&](size_t bytes) {
        char* p = ws + off;
        off = (off + bytes + 255) & ~(size_t)255;
        return p;
    };
    unsigned short* shifted = (unsigned short*)alloc(NTH * 2);
    unsigned short* xin     = (unsigned short*)alloc(NTH * 2);
    unsigned short* zpad    = (unsigned short*)alloc(5 * NTH64 * 2);
    unsigned short* W1t     = (unsigned short*)alloc((size_t)160 * H * 2);
    unsigned short* BcatR   = (unsigned short*)alloc((size_t)H * KC8 * 2);
    unsigned short* BcatK   = (unsigned short*)alloc((size_t)H * KC8 * 2);
    unsigned short* BcatV   = (unsigned short*)alloc((size_t)H * KC8 * 2);
    unsigned short* BcatG   = (unsigned short*)alloc((size_t)H * KC8 * 2);
    unsigned short* Bcat1   = (unsigned short*)alloc((size_t)64 * KCAT * 2);
    float* tdmid            = (float*)alloc((size_t)NROWS * 64 * 4);
    float* bias4            = (float*)alloc(4 * H * 4);
    float* bias0            = (float*)alloc(64 * 4);

    // 1. shifted / xin
    prep_kernel<<<(unsigned)(NTH / (4 * 256)), 256, 0, stream>>>(hidden, attn_x, tmx, shifted, xin);

    // 2. fused weights: transposes + low-rank fusion + biases
    transpose4_kernel<<<dim3(64, 64, 4), 256, 0, stream>>>(
        Wr, Wk, Wv, Wg, BcatR, BcatK, BcatV, BcatG);
    transpose_kernel<<<dim3(5, 64), 256, 0, stream>>>(W1, W1t, H, 160, H);
    transpose_kernel<<<dim3(2, 64), 256, 0, stream>>>(W1d, Bcat1, H, 64, KCAT);
    w2w4_kernel<<<dim3(8, 4, 4), 256, 0, stream>>>(
        W2, Wr, Wk, Wv, Wg, BcatR, BcatK, BcatV, BcatG);
    w2w_kernel<<<dim3(1, 4), 256, 0, stream>>>(W2, W1d, 64, Bcat1, KCAT);
    bias_all_kernel<<<2064, 256, 0, stream>>>(
        BcatR, BcatK, BcatV, BcatG, Bcat1,
        tmaa_r, tmaa_k, tmaa_v, tmaa_g, tmaa_w, bias4, bias0);

    // 3. z = tanh(xin @ W1) -> zpad [5][NROWS][64], cols 32..63 zeroed
    gemm_kernel<4, 1, 2, 10, 0, 2, 0, 1><<<128, 256, 0, stream>>>(
        xin, H, xin, H, H, W1t, H, H, zpad, 0, 1, nullptr);

    // 4. big projections (merged R,K,V,G), 256x256 pipelined
    bigproj8_kernel<<<2048, 512, 0, stream>>>(
        shifted, zpad, BcatR, BcatK, BcatV, BcatG, bias4, out);

    // 5. decay: tdmid = tanh([shifted | z_0] @ Bcat1^T + bias0)   (fp32 out)
    gemm_kernel<4, 1, 1, 4, 1, 2, 1, 0><<<256, 256, 0, stream>>>(
        shifted, H, zpad, 64, H, Bcat1, KCAT, KCAT,
        tdmid, 64, 1, bias0);
    //    td = time_decay + tdmid @ W2d   (fp32 VALU, register-blocked)
    td2_kernel<<<dim3(8, NROWS / 8), 256, 0, stream>>>(
        tdmid, W2d, tdecay, out + 4 * NTH);

    // 6. attn_x_new (exact fp32 copy)
    axnew_kernel<<<32, 256, 0, stream>>>(hidden, out + 5 * NTH);
}

// Round 7
// 1099.092 us; speedup vs baseline: 2.3495x; 1.0214x over previous
//
#include <hip/hip_runtime.h>

#define H 2048
#define TT 4096
#define BB 4
#define NROWS (BB * TT)               // 16384
#define NTH ((size_t)NROWS * H)       // 33,554,432
#define KCAT (H + 32)                 // 2080 (decay path)
#define KC8  (H + 64)                 // 2112 (bigproj, zero-padded)
#define NTH64 ((size_t)NROWS * 64)

typedef __attribute__((ext_vector_type(8))) short bh8;
typedef __attribute__((ext_vector_type(4))) float f32x4;

__device__ inline unsigned short f2bf(float f) {
    union { float f; unsigned u; } v; v.f = f;
    unsigned r = v.u + 0x7fff + ((v.u >> 16) & 1);   // RNE
    return (unsigned short)(r >> 16);
}
__device__ inline float bf2f(unsigned short u) {
    union { unsigned u; float f; } v; v.u = ((unsigned)u) << 16; return v.f;
}
__device__ inline void gload_lds16(const void* g, void* l) {
    __builtin_amdgcn_global_load_lds(
        (const __attribute__((address_space(1))) void*)g,
        (__attribute__((address_space(3))) void*)l, 16, 0, 0);
}

// ---------------- prep: shifted & xin (bf16), vectorized ----------------
__global__ __launch_bounds__(256) void prep_kernel(
    const float* __restrict__ hidden, const float* __restrict__ attn_x,
    const float* __restrict__ tmx,
    unsigned short* __restrict__ shifted, unsigned short* __restrict__ xin) {
    size_t i = ((size_t)blockIdx.x * 256 + threadIdx.x) * 4;
    int n = (int)(i >> 11);
    int h = (int)(i & 2047);
    int t = n & (TT - 1);
    float4 x = *(const float4*)(hidden + i);
    float4 s;
    if (t == 0) {
        int b = n >> 12;
        s = *(const float4*)(attn_x + ((size_t)b << 11) + h);
    } else {
        s = *(const float4*)(hidden + (i - H));
    }
    float4 m = *(const float4*)(tmx + h);
    ushort4 sh, xi;
    sh.x = f2bf(s.x); sh.y = f2bf(s.y); sh.z = f2bf(s.z); sh.w = f2bf(s.w);
    xi.x = f2bf(x.x + (s.x - x.x) * m.x);
    xi.y = f2bf(x.y + (s.y - x.y) * m.y);
    xi.z = f2bf(x.z + (s.z - x.z) * m.z);
    xi.w = f2bf(x.w + (s.w - x.w) * m.w);
    *(ushort4*)(shifted + i) = sh;
    *(ushort4*)(xin + i) = xi;
}

// ---------------- transpose fp32 (R x C) -> bf16 (C x R), out ld = ldo ----
__global__ __launch_bounds__(256) void transpose_kernel(
    const float* __restrict__ in, unsigned short* __restrict__ outp,
    int R, int C, int ldo) {
    __shared__ float tile[32][33];
    int tx = threadIdx.x & 31, ty = threadIdx.x >> 5;
    int r0 = blockIdx.y * 32, c0 = blockIdx.x * 32;
    for (int i = ty; i < 32; i += 8) {
        int r = r0 + i, c = c0 + tx;
        tile[i][tx] = (r < R && c < C) ? in[(size_t)r * C + c] : 0.f;
    }
    __syncthreads();
    for (int i = ty; i < 32; i += 8) {
        int c = c0 + i, r = r0 + tx;
        if (c < C && r < R) outp[(size_t)c * ldo + r] = f2bf(tile[tx][i]);
    }
}

// ---------------- merged transpose of the 4 big weights (H x H, ldo=KC8) --
__global__ __launch_bounds__(256) void transpose4_kernel(
    const float* __restrict__ w0, const float* __restrict__ w1,
    const float* __restrict__ w2, const float* __restrict__ w3,
    unsigned short* __restrict__ d0, unsigned short* __restrict__ d1,
    unsigned short* __restrict__ d2, unsigned short* __restrict__ d3) {
    __shared__ float tile[32][33];
    int bz = blockIdx.z;
    const float* in = bz == 0 ? w0 : bz == 1 ? w1 : bz == 2 ? w2 : w3;
    unsigned short* outp = bz == 0 ? d0 : bz == 1 ? d1 : bz == 2 ? d2 : d3;
    int tx = threadIdx.x & 31, ty = threadIdx.x >> 5;
    int r0 = blockIdx.y * 32, c0 = blockIdx.x * 32;
    for (int i = ty; i < 32; i += 8)
        tile[i][tx] = in[(size_t)(r0 + i) * H + c0 + tx];
    __syncthreads();
    for (int i = ty; i < 32; i += 8)
        outp[(size_t)(c0 + i) * KC8 + r0 + tx] = f2bf(tile[tx][i]);
}

// ------ merged W2W for 4 branches: cols [H..H+32) of Bcat, zeros [H+32..H+64) -
__global__ __launch_bounds__(256) void w2w4_kernel(
    const float* __restrict__ W2,
    const float* __restrict__ w0, const float* __restrict__ w1,
    const float* __restrict__ w2, const float* __restrict__ w3,
    unsigned short* __restrict__ d0, unsigned short* __restrict__ d1,
    unsigned short* __restrict__ d2, unsigned short* __restrict__ d3) {
    __shared__ float lds[8 * H];
    int bz = blockIdx.z;
    const float* W = bz == 0 ? w0 : bz == 1 ? w1 : bz == 2 ? w2 : w3;
    unsigned short* dst = bz == 0 ? d0 : bz == 1 ? d1 : bz == 2 ? d2 : d3;
    const float* W2f = W2 + (size_t)((0x4213 >> (bz * 4)) & 15) * 32 * H;
    const int tid = threadIdx.x;
    const int rg = blockIdx.y;             // group of 8 r's
    for (int i = tid; i < 8 * H; i += 256) lds[i] = W2f[(size_t)rg * 8 * H + i];
    __syncthreads();
    int d = blockIdx.x * 256 + tid;
    float a[8] = {0, 0, 0, 0, 0, 0, 0, 0};
    for (int hh = 0; hh < H; ++hh) {
        float w = W[(size_t)hh * H + d];
#pragma unroll
        for (int r = 0; r < 8; ++r) a[r] += lds[r * H + hh] * w;
    }
#pragma unroll
    for (int r = 0; r < 8; ++r) {
        dst[(size_t)d * KC8 + H + rg * 8 + r] = f2bf(a[r]);
        dst[(size_t)d * KC8 + H + 32 + rg * 8 + r] = 0;   // zero pad
    }
}

// ------------- W2W single (decay): (32 x H) @ (H x 64) -> Bcat1 cols [H..H+32) -
__global__ __launch_bounds__(256) void w2w_kernel(
    const float* __restrict__ W2f, const float* __restrict__ W, int D,
    unsigned short* __restrict__ dst, int ldb) {
    __shared__ float lds[8 * H];
    const int tid = threadIdx.x;
    const int rg = blockIdx.y;
    for (int i = tid; i < 8 * H; i += 256) lds[i] = W2f[(size_t)rg * 8 * H + i];
    __syncthreads();
    int d = blockIdx.x * 256 + tid;
    if (d >= D) return;
    float a[8] = {0, 0, 0, 0, 0, 0, 0, 0};
    for (int hh = 0; hh < H; ++hh) {
        float w = W[(size_t)hh * D + d];
#pragma unroll
        for (int r = 0; r < 8; ++r) a[r] += lds[r * H + hh] * w;
    }
#pragma unroll
    for (int r = 0; r < 8; ++r)
        dst[(size_t)d * ldb + H + rg * 8 + r] = f2bf(a[r]);
}

// -------- bias (merged): wave per row; bias[d] = dot(maa, W[:,d]) via Bcat rows --
__global__ __launch_bounds__(256) void bias_all_kernel(
    const unsigned short* __restrict__ bR, const unsigned short* __restrict__ bK,
    const unsigned short* __restrict__ bV, const unsigned short* __restrict__ bG,
    const unsigned short* __restrict__ b1,
    const float* __restrict__ mR, const float* __restrict__ mK,
    const float* __restrict__ mV, const float* __restrict__ mG,
    const float* __restrict__ mW,
    float* __restrict__ bias4, float* __restrict__ bias0) {
    int wave = threadIdx.x >> 6, lane = threadIdx.x & 63;
    int p = blockIdx.x * 4 + wave;          // 0..8255
    const unsigned short* src; const float* maa; float* dst;
    if (p < 8192) {
        int br = p >> 11, row = p & 2047;
        src = (br == 0 ? bR : br == 1 ? bK : br == 2 ? bV : bG) + (size_t)row * KC8;
        maa = (br == 0 ? mR : br == 1 ? mK : br == 2 ? mV : mG);
        dst = bias4 + br * H + row;
    } else {
        int q = p - 8192;
        if (q >= 64) return;
        src = b1 + (size_t)q * KCAT; maa = mW; dst = bias0 + q;
    }
    float a = 0.f;
#pragma unroll 4
    for (int i = 0; i < 32; ++i) { int h = i * 64 + lane; a += bf2f(src[h]) * maa[h]; }
    for (int s = 32; s; s >>= 1) a += __shfl_xor(a, s);
    if (lane == 0) *dst = a;
}

// ---------------- old-style MFMA GEMM core (z / tdmid) --------------------
template <int WM, int WN, int FM, int FN, int HAS_BIAS, int ACT, int OF32, int ZPAD>
__global__ __launch_bounds__(256) void gemm_kernel(
    const unsigned short* __restrict__ A, int lda,
    const unsigned short* __restrict__ A2, int lda2, int KS,
    const unsigned short* __restrict__ Bt, int ldb, int K,
    void* __restrict__ outp, int ldo, int NT,
    const float* __restrict__ bias) {
    static_assert(WM * WN == 4, "4 waves");
    constexpr int BM = WM * FM * 16;
    constexpr int BN = WN * FN * 16;
    __shared__ unsigned short As[BM * 32];
    __shared__ unsigned short Bs[BN * 32];

    const int nb = gridDim.x;
    const int bid = blockIdx.x;
    const int swz = (bid & 7) * (nb >> 3) + (bid >> 3);   // nb % 8 == 0
    const int mt = swz / NT, nt = swz % NT;
    const int m0 = mt * BM, n0 = nt * BN;

    const int tid = threadIdx.x;
    const int wave = tid >> 6, lane = tid & 63;
    const int l16 = lane & 15, kh = lane >> 4;
    const int wr = wave / WN, wc = wave % WN;

    f32x4 acc[FM][FN] = {};

    constexpr int ACH = BM * 4;   // 16B chunks in A tile
    constexpr int BCH = BN * 4;

    for (int k0 = 0; k0 < K; k0 += 32) {
#pragma unroll
        for (int i = 0; i < (ACH + 255) / 256; ++i) {
            int c = i * 256 + tid;
            if (ACH % 256 == 0 || c < ACH) {
                int row = c >> 2, ck = c & 3;
                int kk = k0 + ck * 8;
                const unsigned short* gp = (kk < KS)
                    ? A  + (size_t)(m0 + row) * lda  + kk
                    : A2 + (size_t)(m0 + row) * lda2 + (kk - KS);
                gload_lds16(gp, As + (size_t)(i * 256 + wave * 64) * 8);
            }
        }
#pragma unroll
        for (int i = 0; i < (BCH + 255) / 256; ++i) {
            int c = i * 256 + tid;
            if (BCH % 256 == 0 || c < BCH) {
                int row = c >> 2, ck = c & 3;
                gload_lds16(Bt + (size_t)(n0 + row) * ldb + k0 + ck * 8,
                            Bs + (size_t)(i * 256 + wave * 64) * 8);
            }
        }
        __syncthreads();
        bh8 av[FM], bv[FN];
#pragma unroll
        for (int mi = 0; mi < FM; ++mi)
            av[mi] = *(const bh8*)((const char*)As + (((wr * FM + mi) * 16 + l16) * 64 + kh * 16));
#pragma unroll
        for (int ni = 0; ni < FN; ++ni)
            bv[ni] = *(const bh8*)((const char*)Bs + (((wc * FN + ni) * 16 + l16) * 64 + kh * 16));
#pragma unroll
        for (int mi = 0; mi < FM; ++mi)
#pragma unroll
            for (int ni = 0; ni < FN; ++ni)
                acc[mi][ni] = __builtin_amdgcn_mfma_f32_16x16x32_bf16(
                    av[mi], bv[ni], acc[mi][ni], 0, 0, 0);
        __syncthreads();
    }

#pragma unroll
    for (int mi = 0; mi < FM; ++mi) {
#pragma unroll
        for (int ni = 0; ni < FN; ++ni) {
            int col = n0 + (wc * FN + ni) * 16 + l16;
            float bcol = HAS_BIAS ? bias[col] : 0.f;
#pragma unroll
            for (int j = 0; j < 4; ++j) {
                int row = m0 + (wr * FM + mi) * 16 + kh * 4 + j;
                float v = acc[mi][ni][j] + bcol;
                if (ACT == 1) v = v * (1.f / (1.f + __expf(-v)));
                else if (ACT == 2) v = tanhf(v);
                if (ZPAD) {
                    int br = col >> 5, cc = col & 31;
                    unsigned short* zp = (unsigned short*)outp
                        + (size_t)br * NTH64 + (size_t)row * 64 + cc;
                    zp[0] = f2bf(v);
                    zp[32] = 0;
                } else if (OF32) {
                    ((float*)outp)[(size_t)row * ldo + col] = v;
                } else {
                    ((unsigned short*)outp)[(size_t)row * ldo + col] = f2bf(v);
                }
            }
        }
    }
}

// ====== bigproj: 256x256 tile, BK=32, 8 waves (2Mx4N), per-wave 128x64 =====
// 4-deep LDS ring, prefetch distance 2 K-tiles, ONE barrier per K-tile,
// software-pipelined LDS->VGPR reads (reads for phase p+1 issued before
// MFMA of phase p; compiler emits counted lgkmcnt -> ds_read || MFMA overlap).
__global__ __launch_bounds__(512, 2) void bigproj8_kernel(
    const unsigned short* __restrict__ A,      // shifted [NROWS][2048]
    const unsigned short* __restrict__ zpad,   // [5][NROWS][64] (cols 32..63 = 0)
    const unsigned short* __restrict__ bt0, const unsigned short* __restrict__ bt1,
    const unsigned short* __restrict__ bt2, const unsigned short* __restrict__ bt3,
    const float* __restrict__ bias4, float* __restrict__ out) {
    constexpr int BUFB = 32768;          // bytes per K-tile buffer (A 16K + B 16K)
    constexpr int NTK = KC8 / 32;        // 66 K-tiles (even)
    __shared__ alignas(16) char lds[4 * BUFB];

    const int bid = blockIdx.x;                      // 2048 blocks
    const int swz = (bid & 7) * 256 + (bid >> 3);    // bijective XCD swizzle
    const int branch = swz >> 9;                     // 0..3 = R,K,V,G
    const int tile = swz & 511;
    const int m0 = (tile >> 3) * 256, n0 = (tile & 7) * 256;

    const unsigned short* Bt = branch == 0 ? bt0 : branch == 1 ? bt1
                             : branch == 2 ? bt2 : bt3;
    const int f = (0x4213 >> (branch * 4)) & 15;     // fidx {3,1,2,4}
    const unsigned short* Az = zpad + (size_t)f * NTH64;

    const int tid = threadIdx.x;
    const int wave = tid >> 6, lane = tid & 63;
    const int l16 = lane & 15, kh = lane >> 4;
    const int wm = wave >> 2, wn = wave & 3;         // 2M x 4N waves
    const int kh16 = kh * 16;
    const int swr = (l16 & 8) << 2;                  // read-side XOR (st_16x32)

    // stage A half of K-tile kt (2 rounds, 1 gload/thread each)
    auto stageA = [&](int kt, char* nb) {
#pragma unroll
        for (int j = 0; j < 2; ++j) {
            int c = j * 512 + tid;                   // 0..1023
            int r = c >> 2, ck = c & 3;
            int kbx = (ck * 16) ^ ((r & 8) << 2);    // byte offset in 64B k-line
            int ke = kt * 32 + (kbx >> 1);
            int row = m0 + r;
            const unsigned short* gp = (ke < 2048)
                ? A  + (size_t)row * 2048 + ke
                : Az + (size_t)row * 64 + (ke - 2048);
            gload_lds16(gp, nb + (size_t)(j * 512 + wave * 64) * 16);
        }
    };
    auto stageB = [&](int kt, char* nb) {
#pragma unroll
        for (int j = 0; j < 2; ++j) {
            int c = j * 512 + tid;
            int r = c >> 2, ck = c & 3;
            int kbx = (ck * 16) ^ ((r & 8) << 2);
            int ke = kt * 32 + (kbx >> 1);
            gload_lds16(Bt + (size_t)(n0 + r) * KC8 + ke,
                        nb + 16384 + (size_t)(j * 512 + wave * 64) * 16);
        }
    };

    f32x4 acc[8][4] = {};
    bh8 avlo[4], avhi[4], bvA[4], bvB[4];

    // prologue: stage K-tiles 0 and 1; read tile 0's phase-A fragments
    stageA(0, lds);        stageB(0, lds);
    stageA(1, lds + BUFB); stageB(1, lds + BUFB);
    asm volatile("s_waitcnt vmcnt(4)" ::: "memory");   // tile 0 complete
    __builtin_amdgcn_s_barrier();
    __builtin_amdgcn_sched_barrier(0);
#pragma unroll
    for (int i = 0; i < 4; ++i) {
        avlo[i] = *(const bh8*)(lds + (wm * 8 + i) * 1024 + l16 * 64 + (kh16 ^ swr));
        bvA[i]  = *(const bh8*)(lds + 16384 + (wn * 4 + i) * 1024 + l16 * 64 + (kh16 ^ swr));
    }

    auto tile_step = [&](int t, bh8 (&bvC)[4], bh8 (&bvN)[4]) {
        const char* Ab = lds + (t & 3) * BUFB;
        char* nb = lds + ((t + 2) & 3) * BUFB;
        const bool doSt = (t + 2) < NTK;

        // ---- phase A: issue avhi reads + stageA, then MFMA lo ----
#pragma unroll
        for (int i = 0; i < 4; ++i)
            avhi[i] = *(const bh8*)(Ab + (wm * 8 + 4 + i) * 1024 + l16 * 64 + (kh16 ^ swr));
        if (doSt) stageA(t + 2, nb);
        __builtin_amdgcn_s_setprio(1);
#pragma unroll
        for (int mi = 0; mi < 4; ++mi)
#pragma unroll
            for (int ni = 0; ni < 4; ++ni)
                acc[mi][ni] = __builtin_amdgcn_mfma_f32_16x16x32_bf16(
                    avlo[mi], bvC[ni], acc[mi][ni], 0, 0, 0);
        __builtin_amdgcn_s_setprio(0);

        // ---- phase B: stageB, tile-boundary sync, issue t+1 reads, MFMA hi --
        if (doSt) stageB(t + 2, nb);
        if (t + 1 < NTK) {
            if (doSt) asm volatile("s_waitcnt vmcnt(4)" ::: "memory");
            else      asm volatile("s_waitcnt vmcnt(0)" ::: "memory");
            __builtin_amdgcn_s_barrier();
            __builtin_amdgcn_sched_barrier(0);
            const char* Ab1 = lds + ((t + 1) & 3) * BUFB;
#pragma unroll
            for (int i = 0; i < 4; ++i) {
                avlo[i] = *(const bh8*)(Ab1 + (wm * 8 + i) * 1024 + l16 * 64 + (kh16 ^ swr));
                bvN[i]  = *(const bh8*)(Ab1 + 16384 + (wn * 4 + i) * 1024 + l16 * 64 + (kh16 ^ swr));
            }
        }
        __builtin_amdgcn_s_setprio(1);
#pragma unroll
        for (int mi = 0; mi < 4; ++mi)
#pragma unroll
            for (int ni = 0; ni < 4; ++ni)
                acc[4 + mi][ni] = __builtin_amdgcn_mfma_f32_16x16x32_bf16(
                    avhi[mi], bvC[ni], acc[4 + mi][ni], 0, 0, 0);
        __builtin_amdgcn_s_setprio(0);
    };

    for (int t = 0; t < NTK; t += 2) {
        tile_step(t,     bvA, bvB);
        tile_step(t + 1, bvB, bvA);
    }

    float* outp = out + (size_t)branch * NTH;
    const float* bias = bias4 + branch * H;
#pragma unroll
    for (int a = 0; a < 8; ++a) {
#pragma unroll
        for (int b = 0; b < 4; ++b) {
            int col = n0 + wn * 64 + b * 16 + l16;
            float bc = bias[col];
#pragma unroll
            for (int j = 0; j < 4; ++j) {
                int row = m0 + wm * 128 + a * 16 + kh * 4 + j;
                float v = acc[a][b][j] + bc;
                if (branch == 3) v = v * (1.f / (1.f + __expf(-v)));   // silu
                outp[(size_t)row * H + col] = v;
            }
        }
    }
}

// ------- td stage 2 (fp32 VALU): out = tdecay + tdmid(N x 64) @ W2d(64 x H) ----
__global__ __launch_bounds__(256) void td2_kernel(
    const float* __restrict__ tdmid, const float* __restrict__ W2d,
    const float* __restrict__ tdecay, float* __restrict__ outp) {
    int col = blockIdx.x * 256 + threadIdx.x;
    int row0 = blockIdx.y * 8;
    float a[8] = {0, 0, 0, 0, 0, 0, 0, 0};
    for (int r = 0; r < 64; ++r) {
        float w = W2d[(size_t)r * H + col];
#pragma unroll
        for (int j = 0; j < 8; ++j)
            a[j] += tdmid[(size_t)(row0 + j) * 64 + r] * w;
    }
    float b = tdecay[col];
#pragma unroll
    for (int j = 0; j < 8; ++j)
        outp[(size_t)(row0 + j) * H + col] = a[j] + b;
}

// ---------------- attn_x_new = hidden[:, -1]  (fp32, exact) ---------------
__global__ __launch_bounds__(256) void axnew_kernel(
    const float* __restrict__ hidden, float* __restrict__ outp) {
    int i = blockIdx.x * 256 + threadIdx.x;       // 0..8191
    int b = i >> 11, h = i & 2047;
    outp[i] = hidden[((size_t)(b * TT + (TT - 1)) << 11) + h];
}

extern "C" void kernel_launch(void* const* d_in, const int* in_sizes, int n_in,
                              void* d_out, int out_size, void* d_ws, size_t ws_size,
                              hipStream_t stream) {
    const float* hidden = (const float*)d_in[0];
    const float* attn_x = (const float*)d_in[1];
    const float* tmx    = (const float*)d_in[4];
    const float* tmaa_w = (const float*)d_in[5];
    const float* tmaa_k = (const float*)d_in[6];
    const float* tmaa_v = (const float*)d_in[7];
    const float* tmaa_r = (const float*)d_in[8];
    const float* tmaa_g = (const float*)d_in[9];
    const float* W1     = (const float*)d_in[10];   // (H,160)
    const float* W2     = (const float*)d_in[11];   // (5,32,H)
    const float* tdecay = (const float*)d_in[12];   // (1,1,H)
    const float* W1d    = (const float*)d_in[13];   // (H,64)
    const float* W2d    = (const float*)d_in[14];   // (64,H)
    const float* Wr     = (const float*)d_in[16];
    const float* Wk     = (const float*)d_in[17];
    const float* Wv     = (const float*)d_in[18];
    const float* Wg     = (const float*)d_in[19];

    float* out = (float*)d_out;     // reference outputs are float32

    char* ws = (char*)d_ws;
    size_t off = 0;
    auto alloc = [&](size_t bytes) {
        char* p = ws + off;
        off = (off + bytes + 255) & ~(size_t)255;
        return p;
    };
    unsigned short* shifted = (unsigned short*)alloc(NTH * 2);
    unsigned short* xin     = (unsigned short*)alloc(NTH * 2);
    unsigned short* zpad    = (unsigned short*)alloc(5 * NTH64 * 2);
    unsigned short* W1t     = (unsigned short*)alloc((size_t)160 * H * 2);
    unsigned short* BcatR   = (unsigned short*)alloc((size_t)H * KC8 * 2);
    unsigned short* BcatK   = (unsigned short*)alloc((size_t)H * KC8 * 2);
    unsigned short* BcatV   = (unsigned short*)alloc((size_t)H * KC8 * 2);
    unsigned short* BcatG   = (unsigned short*)alloc((size_t)H * KC8 * 2);
    unsigned short* Bcat1   = (unsigned short*)alloc((size_t)64 * KCAT * 2);
    float* tdmid            = (float*)alloc((size_t)NROWS * 64 * 4);
    float* bias4            = (float*)alloc(4 * H * 4);
    float* bias0            = (float*)alloc(64 * 4);

    // 1. shifted / xin
    prep_kernel<<<(unsigned)(NTH / (4 * 256)), 256, 0, stream>>>(hidden, attn_x, tmx, shifted, xin);

    // 2. fused weights: transposes + low-rank fusion + biases
    transpose4_kernel<<<dim3(64, 64, 4), 256, 0, stream>>>(
        Wr, Wk, Wv, Wg, BcatR, BcatK, BcatV, BcatG);
    transpose_kernel<<<dim3(5, 64), 256, 0, stream>>>(W1, W1t, H, 160, H);
    transpose_kernel<<<dim3(2, 64), 256, 0, stream>>>(W1d, Bcat1, H, 64, KCAT);
    w2w4_kernel<<<dim3(8, 4, 4), 256, 0, stream>>>(
        W2, Wr, Wk, Wv, Wg, BcatR, BcatK, BcatV, BcatG);
    w2w_kernel<<<dim3(1, 4), 256, 0, stream>>>(W2, W1d, 64, Bcat1, KCAT);
    bias_all_kernel<<<2064, 256, 0, stream>>>(
        BcatR, BcatK, BcatV, BcatG, Bcat1,
        tmaa_r, tmaa_k, tmaa_v, tmaa_g, tmaa_w, bias4, bias0);

    // 3. z = tanh(xin @ W1) -> zpad [5][NROWS][64], cols 32..63 zeroed
    gemm_kernel<4, 1, 2, 10, 0, 2, 0, 1><<<128, 256, 0, stream>>>(
        xin, H, xin, H, H, W1t, H, H, zpad, 0, 1, nullptr);

    // 4. big projections (merged R,K,V,G), 256x256 pipelined
    bigproj8_kernel<<<2048, 512, 0, stream>>>(
        shifted, zpad, BcatR, BcatK, BcatV, BcatG, bias4, out);

    // 5. decay: tdmid = tanh([shifted | z_0] @ Bcat1^T + bias0)   (fp32 out)
    gemm_kernel<4, 1, 1, 4, 1, 2, 1, 0><<<256, 256, 0, stream>>>(
        shifted, H, zpad, 64, H, Bcat1, KCAT, KCAT,
        tdmid, 64, 1, bias0);
    //    td = time_decay + tdmid @ W2d   (fp32 VALU, register-blocked)
    td2_kernel<<<dim3(8, NROWS / 8), 256, 0, stream>>>(
        tdmid, W2d, tdecay, out + 4 * NTH);

    // 6. attn_x_new (exact fp32 copy)
    axnew_kernel<<<32, 256, 0, stream>>>(hidden, out + 5 * NTH);
}

// Round 8
// 1077.520 us; speedup vs baseline: 2.3966x; 1.0200x over previous
//
#include <hip/hip_runtime.h>

#define H 2048
#define TT 4096
#define BB 4
#define NROWS (BB * TT)               // 16384
#define NTH ((size_t)NROWS * H)       // 33,554,432
#define KCAT (H + 32)                 // 2080 (decay path)
#define KC8  (H + 64)                 // 2112 (bigproj, zero-padded)
#define NTH64 ((size_t)NROWS * 64)

typedef __attribute__((ext_vector_type(8))) short bh8;
typedef __attribute__((ext_vector_type(4))) float f32x4;

__device__ inline unsigned short f2bf(float f) {
    union { float f; unsigned u; } v; v.f = f;
    unsigned r = v.u + 0x7fff + ((v.u >> 16) & 1);   // RNE
    return (unsigned short)(r >> 16);
}
__device__ inline float bf2f(unsigned short u) {
    union { unsigned u; float f; } v; v.u = ((unsigned)u) << 16; return v.f;
}
__device__ inline void gload_lds16(const void* g, void* l) {
    __builtin_amdgcn_global_load_lds(
        (const __attribute__((address_space(1))) void*)g,
        (__attribute__((address_space(3))) void*)l, 16, 0, 0);
}

// ---------------- prep: shifted & xin (bf16), vectorized ----------------
__global__ __launch_bounds__(256) void prep_kernel(
    const float* __restrict__ hidden, const float* __restrict__ attn_x,
    const float* __restrict__ tmx,
    unsigned short* __restrict__ shifted, unsigned short* __restrict__ xin) {
    size_t i = ((size_t)blockIdx.x * 256 + threadIdx.x) * 4;
    int n = (int)(i >> 11);
    int h = (int)(i & 2047);
    int t = n & (TT - 1);
    float4 x = *(const float4*)(hidden + i);
    float4 s;
    if (t == 0) {
        int b = n >> 12;
        s = *(const float4*)(attn_x + ((size_t)b << 11) + h);
    } else {
        s = *(const float4*)(hidden + (i - H));
    }
    float4 m = *(const float4*)(tmx + h);
    ushort4 sh, xi;
    sh.x = f2bf(s.x); sh.y = f2bf(s.y); sh.z = f2bf(s.z); sh.w = f2bf(s.w);
    xi.x = f2bf(x.x + (s.x - x.x) * m.x);
    xi.y = f2bf(x.y + (s.y - x.y) * m.y);
    xi.z = f2bf(x.z + (s.z - x.z) * m.z);
    xi.w = f2bf(x.w + (s.w - x.w) * m.w);
    *(ushort4*)(shifted + i) = sh;
    *(ushort4*)(xin + i) = xi;
}

// ---------------- transpose fp32 (R x C) -> bf16 (C x R), out ld = ldo ----
__global__ __launch_bounds__(256) void transpose_kernel(
    const float* __restrict__ in, unsigned short* __restrict__ outp,
    int R, int C, int ldo) {
    __shared__ float tile[32][33];
    int tx = threadIdx.x & 31, ty = threadIdx.x >> 5;
    int r0 = blockIdx.y * 32, c0 = blockIdx.x * 32;
    for (int i = ty; i < 32; i += 8) {
        int r = r0 + i, c = c0 + tx;
        tile[i][tx] = (r < R && c < C) ? in[(size_t)r * C + c] : 0.f;
    }
    __syncthreads();
    for (int i = ty; i < 32; i += 8) {
        int c = c0 + i, r = r0 + tx;
        if (c < C && r < R) outp[(size_t)c * ldo + r] = f2bf(tile[tx][i]);
    }
}

// ---------------- merged transpose of the 4 big weights (H x H, ldo=KC8) --
__global__ __launch_bounds__(256) void transpose4_kernel(
    const float* __restrict__ w0, const float* __restrict__ w1,
    const float* __restrict__ w2, const float* __restrict__ w3,
    unsigned short* __restrict__ d0, unsigned short* __restrict__ d1,
    unsigned short* __restrict__ d2, unsigned short* __restrict__ d3) {
    __shared__ float tile[32][33];
    int bz = blockIdx.z;
    const float* in = bz == 0 ? w0 : bz == 1 ? w1 : bz == 2 ? w2 : w3;
    unsigned short* outp = bz == 0 ? d0 : bz == 1 ? d1 : bz == 2 ? d2 : d3;
    int tx = threadIdx.x & 31, ty = threadIdx.x >> 5;
    int r0 = blockIdx.y * 32, c0 = blockIdx.x * 32;
    for (int i = ty; i < 32; i += 8)
        tile[i][tx] = in[(size_t)(r0 + i) * H + c0 + tx];
    __syncthreads();
    for (int i = ty; i < 32; i += 8)
        outp[(size_t)(c0 + i) * KC8 + r0 + tx] = f2bf(tile[tx][i]);
}

// ------ merged W2W for 4 branches: cols [H..H+32) of Bcat, zeros [H+32..H+64) -
__global__ __launch_bounds__(256) void w2w4_kernel(
    const float* __restrict__ W2,
    const float* __restrict__ w0, const float* __restrict__ w1,
    const float* __restrict__ w2, const float* __restrict__ w3,
    unsigned short* __restrict__ d0, unsigned short* __restrict__ d1,
    unsigned short* __restrict__ d2, unsigned short* __restrict__ d3) {
    __shared__ float lds[8 * H];
    int bz = blockIdx.z;
    const float* W = bz == 0 ? w0 : bz == 1 ? w1 : bz == 2 ? w2 : w3;
    unsigned short* dst = bz == 0 ? d0 : bz == 1 ? d1 : bz == 2 ? d2 : d3;
    const float* W2f = W2 + (size_t)((0x4213 >> (bz * 4)) & 15) * 32 * H;
    const int tid = threadIdx.x;
    const int rg = blockIdx.y;             // group of 8 r's
    for (int i = tid; i < 8 * H; i += 256) lds[i] = W2f[(size_t)rg * 8 * H + i];
    __syncthreads();
    int d = blockIdx.x * 256 + tid;
    float a[8] = {0, 0, 0, 0, 0, 0, 0, 0};
    for (int hh = 0; hh < H; ++hh) {
        float w = W[(size_t)hh * H + d];
#pragma unroll
        for (int r = 0; r < 8; ++r) a[r] += lds[r * H + hh] * w;
    }
#pragma unroll
    for (int r = 0; r < 8; ++r) {
        dst[(size_t)d * KC8 + H + rg * 8 + r] = f2bf(a[r]);
        dst[(size_t)d * KC8 + H + 32 + rg * 8 + r] = 0;   // zero pad
    }
}

// ------------- W2W single (decay): (32 x H) @ (H x 64) -> Bcat1 cols [H..H+32) -
__global__ __launch_bounds__(256) void w2w_kernel(
    const float* __restrict__ W2f, const float* __restrict__ W, int D,
    unsigned short* __restrict__ dst, int ldb) {
    __shared__ float lds[8 * H];
    const int tid = threadIdx.x;
    const int rg = blockIdx.y;
    for (int i = tid; i < 8 * H; i += 256) lds[i] = W2f[(size_t)rg * 8 * H + i];
    __syncthreads();
    int d = blockIdx.x * 256 + tid;
    if (d >= D) return;
    float a[8] = {0, 0, 0, 0, 0, 0, 0, 0};
    for (int hh = 0; hh < H; ++hh) {
        float w = W[(size_t)hh * D + d];
#pragma unroll
        for (int r = 0; r < 8; ++r) a[r] += lds[r * H + hh] * w;
    }
#pragma unroll
    for (int r = 0; r < 8; ++r)
        dst[(size_t)d * ldb + H + rg * 8 + r] = f2bf(a[r]);
}

// -------- bias (merged): wave per row; bias[d] = dot(maa, W[:,d]) via Bcat rows --
__global__ __launch_bounds__(256) void bias_all_kernel(
    const unsigned short* __restrict__ bR, const unsigned short* __restrict__ bK,
    const unsigned short* __restrict__ bV, const unsigned short* __restrict__ bG,
    const unsigned short* __restrict__ b1,
    const float* __restrict__ mR, const float* __restrict__ mK,
    const float* __restrict__ mV, const float* __restrict__ mG,
    const float* __restrict__ mW,
    float* __restrict__ bias4, float* __restrict__ bias0) {
    int wave = threadIdx.x >> 6, lane = threadIdx.x & 63;
    int p = blockIdx.x * 4 + wave;          // 0..8255
    const unsigned short* src; const float* maa; float* dst;
    if (p < 8192) {
        int br = p >> 11, row = p & 2047;
        src = (br == 0 ? bR : br == 1 ? bK : br == 2 ? bV : bG) + (size_t)row * KC8;
        maa = (br == 0 ? mR : br == 1 ? mK : br == 2 ? mV : mG);
        dst = bias4 + br * H + row;
    } else {
        int q = p - 8192;
        if (q >= 64) return;
        src = b1 + (size_t)q * KCAT; maa = mW; dst = bias0 + q;
    }
    float a = 0.f;
#pragma unroll 4
    for (int i = 0; i < 32; ++i) { int h = i * 64 + lane; a += bf2f(src[h]) * maa[h]; }
    for (int s = 32; s; s >>= 1) a += __shfl_xor(a, s);
    if (lane == 0) *dst = a;
}

// ---------------- old-style MFMA GEMM core (z / tdmid) --------------------
template <int WM, int WN, int FM, int FN, int HAS_BIAS, int ACT, int OF32, int ZPAD>
__global__ __launch_bounds__(256) void gemm_kernel(
    const unsigned short* __restrict__ A, int lda,
    const unsigned short* __restrict__ A2, int lda2, int KS,
    const unsigned short* __restrict__ Bt, int ldb, int K,
    void* __restrict__ outp, int ldo, int NT,
    const float* __restrict__ bias) {
    static_assert(WM * WN == 4, "4 waves");
    constexpr int BM = WM * FM * 16;
    constexpr int BN = WN * FN * 16;
    __shared__ unsigned short As[BM * 32];
    __shared__ unsigned short Bs[BN * 32];

    const int nb = gridDim.x;
    const int bid = blockIdx.x;
    const int swz = (bid & 7) * (nb >> 3) + (bid >> 3);   // nb % 8 == 0
    const int mt = swz / NT, nt = swz % NT;
    const int m0 = mt * BM, n0 = nt * BN;

    const int tid = threadIdx.x;
    const int wave = tid >> 6, lane = tid & 63;
    const int l16 = lane & 15, kh = lane >> 4;
    const int wr = wave / WN, wc = wave % WN;

    f32x4 acc[FM][FN] = {};

    constexpr int ACH = BM * 4;   // 16B chunks in A tile
    constexpr int BCH = BN * 4;

    for (int k0 = 0; k0 < K; k0 += 32) {
#pragma unroll
        for (int i = 0; i < (ACH + 255) / 256; ++i) {
            int c = i * 256 + tid;
            if (ACH % 256 == 0 || c < ACH) {
                int row = c >> 2, ck = c & 3;
                int kk = k0 + ck * 8;
                const unsigned short* gp = (kk < KS)
                    ? A  + (size_t)(m0 + row) * lda  + kk
                    : A2 + (size_t)(m0 + row) * lda2 + (kk - KS);
                gload_lds16(gp, As + (size_t)(i * 256 + wave * 64) * 8);
            }
        }
#pragma unroll
        for (int i = 0; i < (BCH + 255) / 256; ++i) {
            int c = i * 256 + tid;
            if (BCH % 256 == 0 || c < BCH) {
                int row = c >> 2, ck = c & 3;
                gload_lds16(Bt + (size_t)(n0 + row) * ldb + k0 + ck * 8,
                            Bs + (size_t)(i * 256 + wave * 64) * 8);
            }
        }
        __syncthreads();
        bh8 av[FM], bv[FN];
#pragma unroll
        for (int mi = 0; mi < FM; ++mi)
            av[mi] = *(const bh8*)((const char*)As + (((wr * FM + mi) * 16 + l16) * 64 + kh * 16));
#pragma unroll
        for (int ni = 0; ni < FN; ++ni)
            bv[ni] = *(const bh8*)((const char*)Bs + (((wc * FN + ni) * 16 + l16) * 64 + kh * 16));
#pragma unroll
        for (int mi = 0; mi < FM; ++mi)
#pragma unroll
            for (int ni = 0; ni < FN; ++ni)
                acc[mi][ni] = __builtin_amdgcn_mfma_f32_16x16x32_bf16(
                    av[mi], bv[ni], acc[mi][ni], 0, 0, 0);
        __syncthreads();
    }

#pragma unroll
    for (int mi = 0; mi < FM; ++mi) {
#pragma unroll
        for (int ni = 0; ni < FN; ++ni) {
            int col = n0 + (wc * FN + ni) * 16 + l16;
            float bcol = HAS_BIAS ? bias[col] : 0.f;
#pragma unroll
            for (int j = 0; j < 4; ++j) {
                int row = m0 + (wr * FM + mi) * 16 + kh * 4 + j;
                float v = acc[mi][ni][j] + bcol;
                if (ACT == 1) v = v * (1.f / (1.f + __expf(-v)));
                else if (ACT == 2) v = tanhf(v);
                if (ZPAD) {
                    int br = col >> 5, cc = col & 31;
                    unsigned short* zp = (unsigned short*)outp
                        + (size_t)br * NTH64 + (size_t)row * 64 + cc;
                    zp[0] = f2bf(v);
                    zp[32] = 0;
                } else if (OF32) {
                    ((float*)outp)[(size_t)row * ldo + col] = v;
                } else {
                    ((unsigned short*)outp)[(size_t)row * ldo + col] = f2bf(v);
                }
            }
        }
    }
}

// ====== bigproj: 256x256 tile, BK=32, 8 waves (2Mx4N), per-wave 128x64 =====
// 4-deep LDS ring, prefetch distance 2 K-tiles, ONE barrier per K-tile,
// software-pipelined LDS->VGPR reads. Staging addresses are incremental
// (per-thread base + kt*64 bytes); A/zpad boundary is tile-aligned (kt>=64).
__global__ __launch_bounds__(512, 2) void bigproj8_kernel(
    const unsigned short* __restrict__ A,      // shifted [NROWS][2048]
    const unsigned short* __restrict__ zpad,   // [5][NROWS][64] (cols 32..63 = 0)
    const unsigned short* __restrict__ bt0, const unsigned short* __restrict__ bt1,
    const unsigned short* __restrict__ bt2, const unsigned short* __restrict__ bt3,
    const float* __restrict__ bias4, float* __restrict__ out) {
    constexpr int BUFB = 32768;          // bytes per K-tile buffer (A 16K + B 16K)
    constexpr int NTK = KC8 / 32;        // 66 K-tiles (even); 0..63 in A, 64..65 in zpad
    __shared__ alignas(16) char lds[4 * BUFB];

    const int bid = blockIdx.x;                      // 2048 blocks
    const int swz = (bid & 7) * 256 + (bid >> 3);    // bijective XCD swizzle
    const int branch = swz >> 9;                     // 0..3 = R,K,V,G
    const int tile = swz & 511;
    const int m0 = (tile >> 3) * 256, n0 = (tile & 7) * 256;

    const unsigned short* Bt = branch == 0 ? bt0 : branch == 1 ? bt1
                             : branch == 2 ? bt2 : bt3;
    const int f = (0x4213 >> (branch * 4)) & 15;     // fidx {3,1,2,4}
    const unsigned short* Az = zpad + (size_t)f * NTH64;

    const int tid = threadIdx.x;
    const int wave = tid >> 6, lane = tid & 63;
    const int l16 = lane & 15, kh = lane >> 4;
    const int wm = wave >> 2, wn = wave & 3;         // 2M x 4N waves
    const int kh16 = kh * 16;
    const int swr = (l16 & 8) << 2;                  // read-side XOR (st_16x32)

    // ---- precomputed staging bases (byte pointers); addr = base + kt*64 ----
    const int rS = tid >> 2;                         // staging row 0..127 (j=0)
    const int kbx = ((tid & 3) * 16) ^ ((rS & 8) << 2);   // src swizzle, j-invariant
    const char* bA0 = (const char*)A  + (size_t)(m0 + rS) * 4096 + kbx;
    const char* bA1 = bA0 + (size_t)128 * 4096;      // j=1: rows 128..255
    const char* bz0 = (const char*)Az + (size_t)(m0 + rS) * 128 + kbx;
    const char* bz1 = bz0 + (size_t)128 * 128;
    const char* bB0 = (const char*)Bt + (size_t)(n0 + rS) * (KC8 * 2) + kbx;
    const char* bB1 = bB0 + (size_t)128 * (KC8 * 2);
    const int dA0 = wave * 1024, dA1 = 8192 + wave * 1024;

    auto stageA = [&](int kt, char* nb) {
        const char *p0, *p1;
        if (kt < 64) { size_t o = (size_t)kt * 64;        p0 = bA0 + o; p1 = bA1 + o; }
        else         { size_t o = (size_t)(kt - 64) * 64; p0 = bz0 + o; p1 = bz1 + o; }
        gload_lds16(p0, nb + dA0);
        gload_lds16(p1, nb + dA1);
    };
    auto stageB = [&](int kt, char* nb) {
        size_t o = (size_t)kt * 64;
        gload_lds16(bB0 + o, nb + 16384 + dA0);
        gload_lds16(bB1 + o, nb + 16384 + dA1);
    };

    f32x4 acc[8][4] = {};
    bh8 avlo[4], avhi[4], bvA[4], bvB[4];

    // prologue: stage K-tiles 0 and 1; read tile 0's phase-A fragments
    stageA(0, lds);        stageB(0, lds);
    stageA(1, lds + BUFB); stageB(1, lds + BUFB);
    asm volatile("s_waitcnt vmcnt(4)" ::: "memory");   // tile 0 complete
    __builtin_amdgcn_s_barrier();
    __builtin_amdgcn_sched_barrier(0);
#pragma unroll
    for (int i = 0; i < 4; ++i) {
        avlo[i] = *(const bh8*)(lds + (wm * 8 + i) * 1024 + l16 * 64 + (kh16 ^ swr));
        bvA[i]  = *(const bh8*)(lds + 16384 + (wn * 4 + i) * 1024 + l16 * 64 + (kh16 ^ swr));
    }

    auto tile_step = [&](int t, bh8 (&bvC)[4], bh8 (&bvN)[4]) {
        const char* Ab = lds + (t & 3) * BUFB;
        char* nb = lds + ((t + 2) & 3) * BUFB;
        const bool doSt = (t + 2) < NTK;

        // ---- phase A: issue avhi reads + stageA, then MFMA lo ----
#pragma unroll
        for (int i = 0; i < 4; ++i)
            avhi[i] = *(const bh8*)(Ab + (wm * 8 + 4 + i) * 1024 + l16 * 64 + (kh16 ^ swr));
        if (doSt) stageA(t + 2, nb);
        __builtin_amdgcn_s_setprio(1);
#pragma unroll
        for (int mi = 0; mi < 4; ++mi)
#pragma unroll
            for (int ni = 0; ni < 4; ++ni)
                acc[mi][ni] = __builtin_amdgcn_mfma_f32_16x16x32_bf16(
                    avlo[mi], bvC[ni], acc[mi][ni], 0, 0, 0);
        __builtin_amdgcn_s_setprio(0);

        // ---- phase B: stageB, tile-boundary sync, issue t+1 reads, MFMA hi --
        if (doSt) stageB(t + 2, nb);
        if (t + 1 < NTK) {
            if (doSt) asm volatile("s_waitcnt vmcnt(4)" ::: "memory");
            else      asm volatile("s_waitcnt vmcnt(0)" ::: "memory");
            __builtin_amdgcn_s_barrier();
            __builtin_amdgcn_sched_barrier(0);
            const char* Ab1 = lds + ((t + 1) & 3) * BUFB;
#pragma unroll
            for (int i = 0; i < 4; ++i) {
                avlo[i] = *(const bh8*)(Ab1 + (wm * 8 + i) * 1024 + l16 * 64 + (kh16 ^ swr));
                bvN[i]  = *(const bh8*)(Ab1 + 16384 + (wn * 4 + i) * 1024 + l16 * 64 + (kh16 ^ swr));
            }
        }
        __builtin_amdgcn_s_setprio(1);
#pragma unroll
        for (int mi = 0; mi < 4; ++mi)
#pragma unroll
            for (int ni = 0; ni < 4; ++ni)
                acc[4 + mi][ni] = __builtin_amdgcn_mfma_f32_16x16x32_bf16(
                    avhi[mi], bvC[ni], acc[4 + mi][ni], 0, 0, 0);
        __builtin_amdgcn_s_setprio(0);
    };

    for (int t = 0; t < NTK; t += 2) {
        tile_step(t,     bvA, bvB);
        tile_step(t + 1, bvB, bvA);
    }

    float* outp = out + (size_t)branch * NTH;
    const float* bias = bias4 + branch * H;
#pragma unroll
    for (int a = 0; a < 8; ++a) {
#pragma unroll
        for (int b = 0; b < 4; ++b) {
            int col = n0 + wn * 64 + b * 16 + l16;
            float bc = bias[col];
#pragma unroll
            for (int j = 0; j < 4; ++j) {
                int row = m0 + wm * 128 + a * 16 + kh * 4 + j;
                float v = acc[a][b][j] + bc;
                if (branch == 3) v = v * (1.f / (1.f + __expf(-v)));   // silu
                outp[(size_t)row * H + col] = v;
            }
        }
    }
}

// ------- td stage 2 (fp32 VALU): out = tdecay + tdmid(N x 64) @ W2d(64 x H) ----
__global__ __launch_bounds__(256) void td2_kernel(
    const float* __restrict__ tdmid, const float* __restrict__ W2d,
    const float* __restrict__ tdecay, float* __restrict__ outp) {
    int col = blockIdx.x * 256 + threadIdx.x;
    int row0 = blockIdx.y * 8;
    float a[8] = {0, 0, 0, 0, 0, 0, 0, 0};
    for (int r = 0; r < 64; ++r) {
        float w = W2d[(size_t)r * H + col];
#pragma unroll
        for (int j = 0; j < 8; ++j)
            a[j] += tdmid[(size_t)(row0 + j) * 64 + r] * w;
    }
    float b = tdecay[col];
#pragma unroll
    for (int j = 0; j < 8; ++j)
        outp[(size_t)(row0 + j) * H + col] = a[j] + b;
}

// ---------------- attn_x_new = hidden[:, -1]  (fp32, exact) ---------------
__global__ __launch_bounds__(256) void axnew_kernel(
    const float* __restrict__ hidden, float* __restrict__ outp) {
    int i = blockIdx.x * 256 + threadIdx.x;       // 0..8191
    int b = i >> 11, h = i & 2047;
    outp[i] = hidden[((size_t)(b * TT + (TT - 1)) << 11) + h];
}

extern "C" void kernel_launch(void* const* d_in, const int* in_sizes, int n_in,
                              void* d_out, int out_size, void* d_ws, size_t ws_size,
                              hipStream_t stream) {
    const float* hidden = (const float*)d_in[0];
    const float* attn_x = (const float*)d_in[1];
    const float* tmx    = (const float*)d_in[4];
    const float* tmaa_w = (const float*)d_in[5];
    const float* tmaa_k = (const float*)d_in[6];
    const float* tmaa_v = (const float*)d_in[7];
    const float* tmaa_r = (const float*)d_in[8];
    const float* tmaa_g = (const float*)d_in[9];
    const float* W1     = (const float*)d_in[10];   // (H,160)
    const float* W2     = (const float*)d_in[11];   // (5,32,H)
    const float* tdecay = (const float*)d_in[12];   // (1,1,H)
    const float* W1d    = (const float*)d_in[13];   // (H,64)
    const float* W2d    = (const float*)d_in[14];   // (64,H)
    const float* Wr     = (const float*)d_in[16];
    const float* Wk     = (const float*)d_in[17];
    const float* Wv     = (const float*)d_in[18];
    const float* Wg     = (const float*)d_in[19];

    float* out = (float*)d_out;     // reference outputs are float32

    char* ws = (char*)d_ws;
    size_t off = 0;
    auto alloc = [&](size_t bytes) {
        char* p = ws + off;
        off = (off + bytes + 255) & ~(size_t)255;
        return p;
    };
    unsigned short* shifted = (unsigned short*)alloc(NTH * 2);
    unsigned short* xin     = (unsigned short*)alloc(NTH * 2);
    unsigned short* zpad    = (unsigned short*)alloc(5 * NTH64 * 2);
    unsigned short* W1t     = (unsigned short*)alloc((size_t)160 * H * 2);
    unsigned short* BcatR   = (unsigned short*)alloc((size_t)H * KC8 * 2);
    unsigned short* BcatK   = (unsigned short*)alloc((size_t)H * KC8 * 2);
    unsigned short* BcatV   = (unsigned short*)alloc((size_t)H * KC8 * 2);
    unsigned short* BcatG   = (unsigned short*)alloc((size_t)H * KC8 * 2);
    unsigned short* Bcat1   = (unsigned short*)alloc((size_t)64 * KCAT * 2);
    float* tdmid            = (float*)alloc((size_t)NROWS * 64 * 4);
    float* bias4            = (float*)alloc(4 * H * 4);
    float* bias0            = (float*)alloc(64 * 4);

    // 1. shifted / xin
    prep_kernel<<<(unsigned)(NTH / (4 * 256)), 256, 0, stream>>>(hidden, attn_x, tmx, shifted, xin);

    // 2. fused weights: transposes + low-rank fusion + biases
    transpose4_kernel<<<dim3(64, 64, 4), 256, 0, stream>>>(
        Wr, Wk, Wv, Wg, BcatR, BcatK, BcatV, BcatG);
    transpose_kernel<<<dim3(5, 64), 256, 0, stream>>>(W1, W1t, H, 160, H);
    transpose_kernel<<<dim3(2, 64), 256, 0, stream>>>(W1d, Bcat1, H, 64, KCAT);
    w2w4_kernel<<<dim3(8, 4, 4), 256, 0, stream>>>(
        W2, Wr, Wk, Wv, Wg, BcatR, BcatK, BcatV, BcatG);
    w2w_kernel<<<dim3(1, 4), 256, 0, stream>>>(W2, W1d, 64, Bcat1, KCAT);
    bias_all_kernel<<<2064, 256, 0, stream>>>(
        BcatR, BcatK, BcatV, BcatG, Bcat1,
        tmaa_r, tmaa_k, tmaa_v, tmaa_g, tmaa_w, bias4, bias0);

    // 3. z = tanh(xin @ W1) -> zpad [5][NROWS][64], cols 32..63 zeroed
    //    BM=64 -> 256 blocks (full chip; was 128)
    gemm_kernel<4, 1, 1, 10, 0, 2, 0, 1><<<256, 256, 0, stream>>>(
        xin, H, xin, H, H, W1t, H, H, zpad, 0, 1, nullptr);

    // 4. big projections (merged R,K,V,G), 256x256 pipelined
    bigproj8_kernel<<<2048, 512, 0, stream>>>(
        shifted, zpad, BcatR, BcatK, BcatV, BcatG, bias4, out);

    // 5. decay: tdmid = tanh([shifted | z_0] @ Bcat1^T + bias0)   (fp32 out)
    gemm_kernel<4, 1, 1, 4, 1, 2, 1, 0><<<256, 256, 0, stream>>>(
        shifted, H, zpad, 64, H, Bcat1, KCAT, KCAT,
        tdmid, 64, 1, bias0);
    //    td = time_decay + tdmid @ W2d   (fp32 VALU, register-blocked)
    td2_kernel<<<dim3(8, NROWS / 8), 256, 0, stream>>>(
        tdmid, W2d, tdecay, out + 4 * NTH);

    // 6. attn_x_new (exact fp32 copy)
    axnew_kernel<<<32, 256, 0, stream>>>(hidden, out + 5 * NTH);
}

// Round 9
// 887.950 us; speedup vs baseline: 2.9082x; 1.2135x over previous
//
#include <hip/hip_runtime.h>

#define H 2048
#define TT 4096
#define BB 4
#define NROWS (BB * TT)               // 16384
#define NTH ((size_t)NROWS * H)       // 33,554,432
#define KCAT (H + 32)                 // 2080 (decay path)
#define KC8  (H + 64)                 // 2112 (bigproj, zero-padded)
#define NTH64 ((size_t)NROWS * 64)

typedef __attribute__((ext_vector_type(8))) short bh8;
typedef __attribute__((ext_vector_type(4))) float f32x4;

__device__ inline unsigned short f2bf(float f) {
    union { float f; unsigned u; } v; v.f = f;
    unsigned r = v.u + 0x7fff + ((v.u >> 16) & 1);   // RNE
    return (unsigned short)(r >> 16);
}
__device__ inline float bf2f(unsigned short u) {
    union { unsigned u; float f; } v; v.u = ((unsigned)u) << 16; return v.f;
}
__device__ inline void gload_lds16(const void* g, void* l) {
    __builtin_amdgcn_global_load_lds(
        (const __attribute__((address_space(1))) void*)g,
        (__attribute__((address_space(3))) void*)l, 16, 0, 0);
}

// ---------------- prep: shifted & xin (bf16), vectorized ----------------
__global__ __launch_bounds__(256) void prep_kernel(
    const float* __restrict__ hidden, const float* __restrict__ attn_x,
    const float* __restrict__ tmx,
    unsigned short* __restrict__ shifted, unsigned short* __restrict__ xin) {
    size_t i = ((size_t)blockIdx.x * 256 + threadIdx.x) * 4;
    int n = (int)(i >> 11);
    int h = (int)(i & 2047);
    int t = n & (TT - 1);
    float4 x = *(const float4*)(hidden + i);
    float4 s;
    if (t == 0) {
        int b = n >> 12;
        s = *(const float4*)(attn_x + ((size_t)b << 11) + h);
    } else {
        s = *(const float4*)(hidden + (i - H));
    }
    float4 m = *(const float4*)(tmx + h);
    ushort4 sh, xi;
    sh.x = f2bf(s.x); sh.y = f2bf(s.y); sh.z = f2bf(s.z); sh.w = f2bf(s.w);
    xi.x = f2bf(x.x + (s.x - x.x) * m.x);
    xi.y = f2bf(x.y + (s.y - x.y) * m.y);
    xi.z = f2bf(x.z + (s.z - x.z) * m.z);
    xi.w = f2bf(x.w + (s.w - x.w) * m.w);
    *(ushort4*)(shifted + i) = sh;
    *(ushort4*)(xin + i) = xi;
}

// ---------------- transpose fp32 (R x C) -> bf16 (C x R), out ld = ldo ----
__global__ __launch_bounds__(256) void transpose_kernel(
    const float* __restrict__ in, unsigned short* __restrict__ outp,
    int R, int C, int ldo) {
    __shared__ float tile[32][33];
    int tx = threadIdx.x & 31, ty = threadIdx.x >> 5;
    int r0 = blockIdx.y * 32, c0 = blockIdx.x * 32;
    for (int i = ty; i < 32; i += 8) {
        int r = r0 + i, c = c0 + tx;
        tile[i][tx] = (r < R && c < C) ? in[(size_t)r * C + c] : 0.f;
    }
    __syncthreads();
    for (int i = ty; i < 32; i += 8) {
        int c = c0 + i, r = r0 + tx;
        if (c < C && r < R) outp[(size_t)c * ldo + r] = f2bf(tile[tx][i]);
    }
}

// ---------------- merged transpose of the 4 big weights (H x H, ldo=KC8) --
__global__ __launch_bounds__(256) void transpose4_kernel(
    const float* __restrict__ w0, const float* __restrict__ w1,
    const float* __restrict__ w2, const float* __restrict__ w3,
    unsigned short* __restrict__ d0, unsigned short* __restrict__ d1,
    unsigned short* __restrict__ d2, unsigned short* __restrict__ d3) {
    __shared__ float tile[32][33];
    int bz = blockIdx.z;
    const float* in = bz == 0 ? w0 : bz == 1 ? w1 : bz == 2 ? w2 : w3;
    unsigned short* outp = bz == 0 ? d0 : bz == 1 ? d1 : bz == 2 ? d2 : d3;
    int tx = threadIdx.x & 31, ty = threadIdx.x >> 5;
    int r0 = blockIdx.y * 32, c0 = blockIdx.x * 32;
    for (int i = ty; i < 32; i += 8)
        tile[i][tx] = in[(size_t)(r0 + i) * H + c0 + tx];
    __syncthreads();
    for (int i = ty; i < 32; i += 8)
        outp[(size_t)(c0 + i) * KC8 + r0 + tx] = f2bf(tile[tx][i]);
}

// ------- W2W stage 1 (K-split partials): part[br][ks][r][d] --------------
// br 0..3: W2[f]@(32xH) x W(HxH); br 4: W2[0] x W1d(Hx64).
__global__ __launch_bounds__(256) void w2wp_kernel(
    const float* __restrict__ W2,
    const float* __restrict__ w0, const float* __restrict__ w1,
    const float* __restrict__ w2, const float* __restrict__ w3,
    const float* __restrict__ W1d,
    float* __restrict__ part) {
    const int br = blockIdx.z, ks = blockIdx.y, dblk = blockIdx.x;
    const int tid = threadIdx.x;
    const float* W; int D;
    if (br < 4) { W = br == 0 ? w0 : br == 1 ? w1 : br == 2 ? w2 : w3; D = H; }
    else        { W = W1d; D = 64; }
    const int f = br < 4 ? ((0x4213 >> (br * 4)) & 15) : 0;
    const float* W2f = W2 + (size_t)f * 32 * H;
    __shared__ float w2s[256][32];       // [kk][r], rows 128B-aligned
    const int k0 = ks * 256;
    for (int idx = tid; idx < 8192; idx += 256) {
        int r = idx & 31, kk = idx >> 5;
        w2s[kk][r] = W2f[(size_t)r * H + k0 + kk];
    }
    __syncthreads();
    int d = dblk * 256 + tid;
    if (d >= D) return;
    float a[32];
#pragma unroll
    for (int r = 0; r < 32; ++r) a[r] = 0.f;
    for (int kk = 0; kk < 256; ++kk) {
        float w = W[(size_t)(k0 + kk) * D + d];
        const float4* w4 = (const float4*)w2s[kk];
#pragma unroll
        for (int rq = 0; rq < 8; ++rq) {
            float4 v = w4[rq];
            a[rq * 4 + 0] += v.x * w;
            a[rq * 4 + 1] += v.y * w;
            a[rq * 4 + 2] += v.z * w;
            a[rq * 4 + 3] += v.w * w;
        }
    }
    float* pp = part + (((size_t)br * 8 + ks) * 32) * 2048 + d;
#pragma unroll
    for (int r = 0; r < 32; ++r) pp[(size_t)r * 2048] = a[r];
}

// ------- W2W stage 2: reduce 8 partials -> bf16 Bcat cols + zero pad ------
__global__ __launch_bounds__(256) void w2wr_kernel(
    const float* __restrict__ part,
    unsigned short* __restrict__ dR, unsigned short* __restrict__ dK,
    unsigned short* __restrict__ dV, unsigned short* __restrict__ dG,
    unsigned short* __restrict__ d1) {
    int gid = blockIdx.x * 256 + threadIdx.x;     // 0..264191
    if (gid < 262144) {
        int br = gid >> 16, rem = gid & 65535;
        int r = rem >> 11, d = rem & 2047;
        float s = 0.f;
#pragma unroll
        for (int ks = 0; ks < 8; ++ks)
            s += part[(((size_t)br * 8 + ks) * 32 + r) * 2048 + d];
        unsigned short* dst = br == 0 ? dR : br == 1 ? dK : br == 2 ? dV : dG;
        dst[(size_t)d * KC8 + H + r] = f2bf(s);
        dst[(size_t)d * KC8 + H + 32 + r] = 0;    // zero pad
    } else {
        int q = gid - 262144;                      // 0..2047
        int r = q >> 6, d = q & 63;
        float s = 0.f;
#pragma unroll
        for (int ks = 0; ks < 8; ++ks)
            s += part[(((size_t)4 * 8 + ks) * 32 + r) * 2048 + d];
        d1[(size_t)d * KCAT + H + r] = f2bf(s);
    }
}

// -------- bias (merged): wave per row; bias[d] = dot(maa, W[:,d]) via Bcat rows --
__global__ __launch_bounds__(256) void bias_all_kernel(
    const unsigned short* __restrict__ bR, const unsigned short* __restrict__ bK,
    const unsigned short* __restrict__ bV, const unsigned short* __restrict__ bG,
    const unsigned short* __restrict__ b1,
    const float* __restrict__ mR, const float* __restrict__ mK,
    const float* __restrict__ mV, const float* __restrict__ mG,
    const float* __restrict__ mW,
    float* __restrict__ bias4, float* __restrict__ bias0) {
    int wave = threadIdx.x >> 6, lane = threadIdx.x & 63;
    int p = blockIdx.x * 4 + wave;          // 0..8255
    const unsigned short* src; const float* maa; float* dst;
    if (p < 8192) {
        int br = p >> 11, row = p & 2047;
        src = (br == 0 ? bR : br == 1 ? bK : br == 2 ? bV : bG) + (size_t)row * KC8;
        maa = (br == 0 ? mR : br == 1 ? mK : br == 2 ? mV : mG);
        dst = bias4 + br * H + row;
    } else {
        int q = p - 8192;
        if (q >= 64) return;
        src = b1 + (size_t)q * KCAT; maa = mW; dst = bias0 + q;
    }
    float a = 0.f;
#pragma unroll 4
    for (int i = 0; i < 32; ++i) { int h = i * 64 + lane; a += bf2f(src[h]) * maa[h]; }
    for (int s = 32; s; s >>= 1) a += __shfl_xor(a, s);
    if (lane == 0) *dst = a;
}

// ---------------- old-style MFMA GEMM core (z / tdmid) --------------------
template <int WM, int WN, int FM, int FN, int HAS_BIAS, int ACT, int OF32, int ZPAD>
__global__ __launch_bounds__(256) void gemm_kernel(
    const unsigned short* __restrict__ A, int lda,
    const unsigned short* __restrict__ A2, int lda2, int KS,
    const unsigned short* __restrict__ Bt, int ldb, int K,
    void* __restrict__ outp, int ldo, int NT,
    const float* __restrict__ bias) {
    static_assert(WM * WN == 4, "4 waves");
    constexpr int BM = WM * FM * 16;
    constexpr int BN = WN * FN * 16;
    __shared__ unsigned short As[BM * 32];
    __shared__ unsigned short Bs[BN * 32];

    const int nb = gridDim.x;
    const int bid = blockIdx.x;
    const int swz = (bid & 7) * (nb >> 3) + (bid >> 3);   // nb % 8 == 0
    const int mt = swz / NT, nt = swz % NT;
    const int m0 = mt * BM, n0 = nt * BN;

    const int tid = threadIdx.x;
    const int wave = tid >> 6, lane = tid & 63;
    const int l16 = lane & 15, kh = lane >> 4;
    const int wr = wave / WN, wc = wave % WN;

    f32x4 acc[FM][FN] = {};

    constexpr int ACH = BM * 4;   // 16B chunks in A tile
    constexpr int BCH = BN * 4;

    for (int k0 = 0; k0 < K; k0 += 32) {
#pragma unroll
        for (int i = 0; i < (ACH + 255) / 256; ++i) {
            int c = i * 256 + tid;
            if (ACH % 256 == 0 || c < ACH) {
                int row = c >> 2, ck = c & 3;
                int kk = k0 + ck * 8;
                const unsigned short* gp = (kk < KS)
                    ? A  + (size_t)(m0 + row) * lda  + kk
                    : A2 + (size_t)(m0 + row) * lda2 + (kk - KS);
                gload_lds16(gp, As + (size_t)(i * 256 + wave * 64) * 8);
            }
        }
#pragma unroll
        for (int i = 0; i < (BCH + 255) / 256; ++i) {
            int c = i * 256 + tid;
            if (BCH % 256 == 0 || c < BCH) {
                int row = c >> 2, ck = c & 3;
                gload_lds16(Bt + (size_t)(n0 + row) * ldb + k0 + ck * 8,
                            Bs + (size_t)(i * 256 + wave * 64) * 8);
            }
        }
        __syncthreads();
        bh8 av[FM], bv[FN];
#pragma unroll
        for (int mi = 0; mi < FM; ++mi)
            av[mi] = *(const bh8*)((const char*)As + (((wr * FM + mi) * 16 + l16) * 64 + kh * 16));
#pragma unroll
        for (int ni = 0; ni < FN; ++ni)
            bv[ni] = *(const bh8*)((const char*)Bs + (((wc * FN + ni) * 16 + l16) * 64 + kh * 16));
#pragma unroll
        for (int mi = 0; mi < FM; ++mi)
#pragma unroll
            for (int ni = 0; ni < FN; ++ni)
                acc[mi][ni] = __builtin_amdgcn_mfma_f32_16x16x32_bf16(
                    av[mi], bv[ni], acc[mi][ni], 0, 0, 0);
        __syncthreads();
    }

#pragma unroll
    for (int mi = 0; mi < FM; ++mi) {
#pragma unroll
        for (int ni = 0; ni < FN; ++ni) {
            int col = n0 + (wc * FN + ni) * 16 + l16;
            float bcol = HAS_BIAS ? bias[col] : 0.f;
#pragma unroll
            for (int j = 0; j < 4; ++j) {
                int row = m0 + (wr * FM + mi) * 16 + kh * 4 + j;
                float v = acc[mi][ni][j] + bcol;
                if (ACT == 1) v = v * (1.f / (1.f + __expf(-v)));
                else if (ACT == 2) v = tanhf(v);
                if (ZPAD) {
                    int br = col >> 5, cc = col & 31;
                    unsigned short* zp = (unsigned short*)outp
                        + (size_t)br * NTH64 + (size_t)row * 64 + cc;
                    zp[0] = f2bf(v);
                    zp[32] = 0;
                } else if (OF32) {
                    ((float*)outp)[(size_t)row * ldo + col] = v;
                } else {
                    ((unsigned short*)outp)[(size_t)row * ldo + col] = f2bf(v);
                }
            }
        }
    }
}

// ====== bigproj: 256x256 tile, BK=64, 8 waves (2Mx4N), per-wave 128x64 =====
// 2-buffer LDS ring (2 x 64KB), prefetch distance 1, ONE barrier per K=64,
// all 8 staging loads issued in sub-phases 0-1 (>=1200cyc cover), lgkm drain
// before the boundary barrier (WAR-safe), register-recycled fragments.
__global__ __launch_bounds__(512, 2) void bigproj8_kernel(
    const unsigned short* __restrict__ A,      // shifted [NROWS][2048]
    const unsigned short* __restrict__ zpad,   // [5][NROWS][64] (cols 32..63 = 0)
    const unsigned short* __restrict__ bt0, const unsigned short* __restrict__ bt1,
    const unsigned short* __restrict__ bt2, const unsigned short* __restrict__ bt3,
    const float* __restrict__ bias4, float* __restrict__ out) {
    constexpr int BUFB = 65536;          // per K-tile: A 2x16K + B 2x16K
    constexpr int NTK = KC8 / 64;        // 33; kt<32 in A, kt==32 in zpad
    __shared__ alignas(16) char lds[2 * BUFB];

    const int bid = blockIdx.x;                      // 2048 blocks
    const int swz = (bid & 7) * 256 + (bid >> 3);    // bijective XCD swizzle
    const int branch = swz >> 9;                     // 0..3 = R,K,V,G
    const int tile = swz & 511;
    const int m0 = (tile >> 3) * 256, n0 = (tile & 7) * 256;

    const unsigned short* Bt = branch == 0 ? bt0 : branch == 1 ? bt1
                             : branch == 2 ? bt2 : bt3;
    const int f = (0x4213 >> (branch * 4)) & 15;     // fidx {3,1,2,4}
    const unsigned short* Az = zpad + (size_t)f * NTH64;

    const int tid = threadIdx.x;
    const int wave = tid >> 6, lane = tid & 63;
    const int l16 = lane & 15, kh = lane >> 4;
    const int wm = wave >> 2, wn = wave & 3;         // 2M x 4N waves
    const int kh16 = kh * 16;
    const int swr = (l16 & 8) << 2;                  // read-side XOR (st_16x32)

    // staging bases: addr = base + kt*128 + s*64 (s = K-half)
    const int rS = tid >> 2;
    const int kbx = ((tid & 3) * 16) ^ ((rS & 8) << 2);
    const char* bA0 = (const char*)A  + (size_t)(m0 + rS) * 4096 + kbx;
    const char* bA1 = bA0 + (size_t)128 * 4096;
    const char* bz0 = (const char*)Az + (size_t)(m0 + rS) * 128 + kbx;
    const char* bz1 = bz0 + (size_t)128 * 128;
    const char* bB0 = (const char*)Bt + (size_t)(n0 + rS) * (KC8 * 2) + kbx;
    const char* bB1 = bB0 + (size_t)128 * (KC8 * 2);
    const int dA0 = wave * 1024, dA1 = 8192 + wave * 1024;

    auto stageA = [&](int kt, char* nb) {
        const char *p0, *p1;
        if (kt < 32) { size_t o = (size_t)kt * 128; p0 = bA0 + o; p1 = bA1 + o; }
        else         { p0 = bz0; p1 = bz1; }
#pragma unroll
        for (int s = 0; s < 2; ++s) {
            gload_lds16(p0 + s * 64, nb + s * 16384 + dA0);
            gload_lds16(p1 + s * 64, nb + s * 16384 + dA1);
        }
    };
    auto stageB = [&](int kt, char* nb) {
        size_t o = (size_t)kt * 128;
#pragma unroll
        for (int s = 0; s < 2; ++s) {
            gload_lds16(bB0 + o + s * 64, nb + 32768 + s * 16384 + dA0);
            gload_lds16(bB1 + o + s * 64, nb + 32768 + s * 16384 + dA1);
        }
    };
    auto rdA = [&](const char* bb, int s, int g) {
        return *(const bh8*)(bb + s * 16384 + g * 1024 + l16 * 64 + (kh16 ^ swr));
    };
    auto rdB = [&](const char* bb, int s, int g) {
        return *(const bh8*)(bb + 32768 + s * 16384 + g * 1024 + l16 * 64 + (kh16 ^ swr));
    };

    f32x4 acc[8][4] = {};
    bh8 avX[4], avY[4], bv0[4], bv1[4];

    // prologue: stage tiles 0,1; wait tile 0; read its first fragments
    stageA(0, lds);        stageB(0, lds);
    stageA(1, lds + BUFB); stageB(1, lds + BUFB);
    asm volatile("s_waitcnt vmcnt(8)" ::: "memory");
    __builtin_amdgcn_s_barrier();
    __builtin_amdgcn_sched_barrier(0);
#pragma unroll
    for (int i = 0; i < 4; ++i) {
        avX[i] = rdA(lds, 0, wm * 8 + i);
        bv0[i] = rdB(lds, 0, wn * 4 + i);
    }

    for (int t = 0; t < NTK; ++t) {
        const char* cb = lds + (t & 1) * BUFB;
        char* nb = lds + ((t + 1) & 1) * BUFB;
        const bool doSt = (t + 1) < NTK;

        // P0: read A-hi(k0); stage next A; MFMA lo(k0)
#pragma unroll
        for (int i = 0; i < 4; ++i) avY[i] = rdA(cb, 0, wm * 8 + 4 + i);
        if (doSt) stageA(t + 1, nb);
        __builtin_amdgcn_s_setprio(1);
#pragma unroll
        for (int mi = 0; mi < 4; ++mi)
#pragma unroll
            for (int ni = 0; ni < 4; ++ni)
                acc[mi][ni] = __builtin_amdgcn_mfma_f32_16x16x32_bf16(
                    avX[mi], bv0[ni], acc[mi][ni], 0, 0, 0);
        __builtin_amdgcn_s_setprio(0);

        // P1: read A-lo(k1), B(k1); stage next B; MFMA hi(k0)
#pragma unroll
        for (int i = 0; i < 4; ++i) {
            avX[i] = rdA(cb, 1, wm * 8 + i);
            bv1[i] = rdB(cb, 1, wn * 4 + i);
        }
        if (doSt) stageB(t + 1, nb);
        __builtin_amdgcn_s_setprio(1);
#pragma unroll
        for (int mi = 0; mi < 4; ++mi)
#pragma unroll
            for (int ni = 0; ni < 4; ++ni)
                acc[4 + mi][ni] = __builtin_amdgcn_mfma_f32_16x16x32_bf16(
                    avY[mi], bv0[ni], acc[4 + mi][ni], 0, 0, 0);
        __builtin_amdgcn_s_setprio(0);

        // P2: read A-hi(k1); MFMA lo(k1)
#pragma unroll
        for (int i = 0; i < 4; ++i) avY[i] = rdA(cb, 1, wm * 8 + 4 + i);
        __builtin_amdgcn_s_setprio(1);
#pragma unroll
        for (int mi = 0; mi < 4; ++mi)
#pragma unroll
            for (int ni = 0; ni < 4; ++ni)
                acc[mi][ni] = __builtin_amdgcn_mfma_f32_16x16x32_bf16(
                    avX[mi], bv1[ni], acc[mi][ni], 0, 0, 0);
        __builtin_amdgcn_s_setprio(0);

        // P3: boundary (drain LDS reads, wait next tile's DMA, barrier),
        //     read next tile's first frags, MFMA hi(k1)
        if (doSt) {
            asm volatile("s_waitcnt vmcnt(0) lgkmcnt(0)" ::: "memory");
            __builtin_amdgcn_s_barrier();
            __builtin_amdgcn_sched_barrier(0);
#pragma unroll
            for (int i = 0; i < 4; ++i) {
                avX[i] = rdA(nb, 0, wm * 8 + i);
                bv0[i] = rdB(nb, 0, wn * 4 + i);
            }
        }
        __builtin_amdgcn_s_setprio(1);
#pragma unroll
        for (int mi = 0; mi < 4; ++mi)
#pragma unroll
            for (int ni = 0; ni < 4; ++ni)
                acc[4 + mi][ni] = __builtin_amdgcn_mfma_f32_16x16x32_bf16(
                    avY[mi], bv1[ni], acc[4 + mi][ni], 0, 0, 0);
        __builtin_amdgcn_s_setprio(0);
    }

    float* outp = out + (size_t)branch * NTH;
    const float* bias = bias4 + branch * H;
#pragma unroll
    for (int a = 0; a < 8; ++a) {
#pragma unroll
        for (int b = 0; b < 4; ++b) {
            int col = n0 + wn * 64 + b * 16 + l16;
            float bc = bias[col];
#pragma unroll
            for (int j = 0; j < 4; ++j) {
                int row = m0 + wm * 128 + a * 16 + kh * 4 + j;
                float v = acc[a][b][j] + bc;
                if (branch == 3) v = v * (1.f / (1.f + __expf(-v)));   // silu
                outp[(size_t)row * H + col] = v;
            }
        }
    }
}

// ------- td stage 2 (fp32 VALU): out = tdecay + tdmid(N x 64) @ W2d(64 x H) ----
__global__ __launch_bounds__(256) void td2_kernel(
    const float* __restrict__ tdmid, const float* __restrict__ W2d,
    const float* __restrict__ tdecay, float* __restrict__ outp) {
    int col = blockIdx.x * 256 + threadIdx.x;
    int row0 = blockIdx.y * 8;
    float a[8] = {0, 0, 0, 0, 0, 0, 0, 0};
    for (int r = 0; r < 64; ++r) {
        float w = W2d[(size_t)r * H + col];
#pragma unroll
        for (int j = 0; j < 8; ++j)
            a[j] += tdmid[(size_t)(row0 + j) * 64 + r] * w;
    }
    float b = tdecay[col];
#pragma unroll
    for (int j = 0; j < 8; ++j)
        outp[(size_t)(row0 + j) * H + col] = a[j] + b;
}

// ---------------- attn_x_new = hidden[:, -1]  (fp32, exact) ---------------
__global__ __launch_bounds__(256) void axnew_kernel(
    const float* __restrict__ hidden, float* __restrict__ outp) {
    int i = blockIdx.x * 256 + threadIdx.x;       // 0..8191
    int b = i >> 11, h = i & 2047;
    outp[i] = hidden[((size_t)(b * TT + (TT - 1)) << 11) + h];
}

extern "C" void kernel_launch(void* const* d_in, const int* in_sizes, int n_in,
                              void* d_out, int out_size, void* d_ws, size_t ws_size,
                              hipStream_t stream) {
    const float* hidden = (const float*)d_in[0];
    const float* attn_x = (const float*)d_in[1];
    const float* tmx    = (const float*)d_in[4];
    const float* tmaa_w = (const float*)d_in[5];
    const float* tmaa_k = (const float*)d_in[6];
    const float* tmaa_v = (const float*)d_in[7];
    const float* tmaa_r = (const float*)d_in[8];
    const float* tmaa_g = (const float*)d_in[9];
    const float* W1     = (const float*)d_in[10];   // (H,160)
    const float* W2     = (const float*)d_in[11];   // (5,32,H)
    const float* tdecay = (const float*)d_in[12];   // (1,1,H)
    const float* W1d    = (const float*)d_in[13];   // (H,64)
    const float* W2d    = (const float*)d_in[14];   // (64,H)
    const float* Wr     = (const float*)d_in[16];
    const float* Wk     = (const float*)d_in[17];
    const float* Wv     = (const float*)d_in[18];
    const float* Wg     = (const float*)d_in[19];

    float* out = (float*)d_out;     // reference outputs are float32

    char* ws = (char*)d_ws;
    size_t off = 0;
    auto alloc = [&](size_t bytes) {
        char* p = ws + off;
        off = (off + bytes + 255) & ~(size_t)255;
        return p;
    };
    unsigned short* shifted = (unsigned short*)alloc(NTH * 2);
    unsigned short* xin     = (unsigned short*)alloc(NTH * 2);
    unsigned short* zpad    = (unsigned short*)alloc(5 * NTH64 * 2);
    unsigned short* W1t     = (unsigned short*)alloc((size_t)160 * H * 2);
    unsigned short* BcatR   = (unsigned short*)alloc((size_t)H * KC8 * 2);
    unsigned short* BcatK   = (unsigned short*)alloc((size_t)H * KC8 * 2);
    unsigned short* BcatV   = (unsigned short*)alloc((size_t)H * KC8 * 2);
    unsigned short* BcatG   = (unsigned short*)alloc((size_t)H * KC8 * 2);
    unsigned short* Bcat1   = (unsigned short*)alloc((size_t)64 * KCAT * 2);
    float* tdmid            = (float*)alloc((size_t)NROWS * 64 * 4);
    float* part             = (float*)alloc((size_t)5 * 8 * 32 * 2048 * 4);
    float* bias4            = (float*)alloc(4 * H * 4);
    float* bias0            = (float*)alloc(64 * 4);

    // 1. shifted / xin
    prep_kernel<<<(unsigned)(NTH / (4 * 256)), 256, 0, stream>>>(hidden, attn_x, tmx, shifted, xin);

    // 2. fused weights: transposes + K-split low-rank fusion + biases
    transpose4_kernel<<<dim3(64, 64, 4), 256, 0, stream>>>(
        Wr, Wk, Wv, Wg, BcatR, BcatK, BcatV, BcatG);
    transpose_kernel<<<dim3(5, 64), 256, 0, stream>>>(W1, W1t, H, 160, H);
    transpose_kernel<<<dim3(2, 64), 256, 0, stream>>>(W1d, Bcat1, H, 64, KCAT);
    w2wp_kernel<<<dim3(8, 8, 5), 256, 0, stream>>>(
        W2, Wr, Wk, Wv, Wg, W1d, part);
    w2wr_kernel<<<1032, 256, 0, stream>>>(
        part, BcatR, BcatK, BcatV, BcatG, Bcat1);
    bias_all_kernel<<<2064, 256, 0, stream>>>(
        BcatR, BcatK, BcatV, BcatG, Bcat1,
        tmaa_r, tmaa_k, tmaa_v, tmaa_g, tmaa_w, bias4, bias0);

    // 3. z = tanh(xin @ W1) -> zpad [5][NROWS][64], cols 32..63 zeroed
    gemm_kernel<4, 1, 1, 10, 0, 2, 0, 1><<<256, 256, 0, stream>>>(
        xin, H, xin, H, H, W1t, H, H, zpad, 0, 1, nullptr);

    // 4. big projections (merged R,K,V,G), 256x256 BK=64 pipelined
    bigproj8_kernel<<<2048, 512, 0, stream>>>(
        shifted, zpad, BcatR, BcatK, BcatV, BcatG, bias4, out);

    // 5. decay: tdmid = tanh([shifted | z_0] @ Bcat1^T + bias0)   (fp32 out)
    gemm_kernel<4, 1, 1, 4, 1, 2, 1, 0><<<256, 256, 0, stream>>>(
        shifted, H, zpad, 64, H, Bcat1, KCAT, KCAT,
        tdmid, 64, 1, bias0);
    //    td = time_decay + tdmid @ W2d   (fp32 VALU, register-blocked)
    td2_kernel<<<dim3(8, NROWS / 8), 256, 0, stream>>>(
        tdmid, W2d, tdecay, out + 4 * NTH);

    // 6. attn_x_new (exact fp32 copy)
    axnew_kernel<<<32, 256, 0, stream>>>(hidden, out + 5 * NTH);
}